// Round 2
// baseline (507.775 us; speedup 1.0000x reference)
//
#include <hip/hip_runtime.h>

#define NROWS 16384
#define NFEAT 4096
#define RPB   16          // rows per block in kron kernels
#define SLOT  16384       // bytes per output-row slot in d_out

typedef __attribute__((ext_vector_type(8))) short          bfrag8;  // 8 x bf16
typedef __attribute__((ext_vector_type(4))) float          fvec4;
typedef __attribute__((ext_vector_type(4))) unsigned short usvec4;
typedef __attribute__((ext_vector_type(8))) unsigned short usvec8;

// ---- scratch lives in the HIGH half (bytes 8192..16384) of d_out row slots ----
// region = consecutive slot-high-halves starting at `row`; virtual float idx v:
//   float v  ->  byte (row + v/2048)*SLOT + 8192 + (v%2048)*4
// Regions (rows):
//   bn0 partials  : rows 4p..4p+3   (p<256)     [bn0part W -> prep0 R]   (rows 0..1023)
//   C2T           : rows 1028-1029               [prep0 W -> prep2b R]
//   scale0|shift0 : rows 1032-1035               [prep0 W -> kron1 R]
//   C1T           : rows 1036-1037               [prep0 W -> kron1 R]
//   scale1|shift1 : rows 1044-1047 (staging)     [prep2a W -> prep2b R]
//   bn1 partials  : rows 16i..16i+3 (i<1024)    [kron1 W -> prep2a R]
//   per-block copy: rows 16i+10..16i+15          [prep2b W -> kron2(i) R]
// Row-coloring: partial writes hit rows ==0..3 (mod 16); replicas ==10..15;
// shared regions sit at rows ==4..13 of slots 1028..1047 -> no W/R overlap at
// any stage (verified per stage).

__device__ __forceinline__ float* HIp(char* base, int row, int v) {
  return (float*)(base + (size_t)(row + (v >> 11)) * SLOT + 8192 + ((size_t)(v & 2047) << 2));
}

__device__ __forceinline__ unsigned short f2bf_bits(float f) {
  unsigned u = __builtin_bit_cast(unsigned, f);
  u += 0x7FFFu + ((u >> 16) & 1u);          // round-to-nearest-even
  return (unsigned short)(u >> 16);
}
__device__ __forceinline__ float bf2f(unsigned short b) {
  return __builtin_bit_cast(float, ((unsigned)b) << 16);
}

// ---------------- BN0 partial sums (no atomics) ----------------
__global__ __launch_bounds__(256) void k_bn0part(const float* __restrict__ x,
                                                 char* base) {
  const int t = threadIdx.x, p = blockIdx.x;
  fvec4 s[4], sq[4];
#pragma unroll
  for (int q = 0; q < 4; ++q) { s[q] = fvec4{0.f,0.f,0.f,0.f}; sq[q] = s[q]; }
  for (int r = p * 64; r < p * 64 + 64; ++r) {
    const fvec4* row = (const fvec4*)(x + (size_t)r * NFEAT);
#pragma unroll
    for (int q = 0; q < 4; ++q) {
      fvec4 v = row[t + 256 * q];
      s[q] += v; sq[q] += v * v;
    }
  }
#pragma unroll
  for (int q = 0; q < 4; ++q) {
    int f0 = (t + 256 * q) * 4;
    *(fvec4*)HIp(base, 4 * p, f0)        = s[q];
    *(fvec4*)HIp(base, 4 * p, 4096 + f0) = sq[q];
  }
}

// ---------------- prep0: reduce bn0 partials -> scale0/shift0; C1T; C2T ----------------
__global__ __launch_bounds__(256) void k_prep0(const float* __restrict__ g0,
                                               const float* __restrict__ b0,
                                               const float* __restrict__ lb1,
                                               const float* __restrict__ rw1,
                                               const float* __restrict__ rb1,
                                               const float* __restrict__ lb2,
                                               const float* __restrict__ rw2,
                                               const float* __restrict__ rb2,
                                               char* base) {
  const int idx  = (blockIdx.x & 15) * 256 + threadIdx.x;   // 0..4095
  const int part = blockIdx.x >> 4;                          // 0,1,2
  if (part == 0) {
    float sum = 0.f, ss = 0.f;
    for (int p = 0; p < 256; ++p) {
      sum += *HIp(base, 4 * p, idx);
      ss  += *HIp(base, 4 * p, 4096 + idx);
    }
    float mean = sum * (1.0f / NROWS);
    float var  = ss * (1.0f / NROWS) - mean * mean;
    float sc   = g0[idx] * rsqrtf(var + 1e-3f);
    *HIp(base, 1032, idx)        = sc;
    *HIp(base, 1032, 4096 + idx) = b0[idx] - mean * sc;
  } else {
    const float* lb = (part == 1) ? lb1 : lb2;
    const float* rw = (part == 1) ? rw1 : rw2;
    const float* rb = (part == 1) ? rb1 : rb2;
    int r = idx >> 6, o = idx & 63;
    float acc = rb[o * 64 + r];
    for (int j = 0; j < 64; ++j) acc += lb[o * 64 + j] * rw[j * 64 + r];
    *HIp(base, (part == 1) ? 1036 : 1028, idx) = acc;        // CT[r][o], idx=r*64+o
  }
}

// ---------------- prep2a: reduce bn1 partials -> scale1/shift1 staging ----------------
__global__ __launch_bounds__(256) void k_prep2a(const float* __restrict__ g1,
                                                const float* __restrict__ b1,
                                                char* base) {
  const int idx = blockIdx.x * 256 + threadIdx.x;            // 16 blocks -> 0..4095
  float sum = 0.f, ss = 0.f;
  for (int i = 0; i < 1024; ++i) {
    sum += *HIp(base, 16 * i, idx);
    ss  += *HIp(base, 16 * i, 4096 + idx);
  }
  float mean = sum * (1.0f / NROWS);
  float var  = ss * (1.0f / NROWS) - mean * mean;
  float sc   = g1[idx] * rsqrtf(var + 1e-3f);
  *HIp(base, 1044, idx)        = sc;
  *HIp(base, 1044, 4096 + idx) = b1[idx] - mean * sc;
}

// ---------------- prep2b: replicate scale1|shift1|C2T into each kron2 block's rows ----------------
__global__ __launch_bounds__(256) void k_prep2b(char* base) {
  const int t = threadIdx.x, i = blockIdx.x;                 // 1024 blocks
#pragma unroll
  for (int c = 0; c < 12; ++c) {
    int v = (t + 256 * c) * 4;                               // 0..12284
    fvec4 val = (v < 8192) ? *(fvec4*)HIp(base, 1044, v)
                           : *(fvec4*)HIp(base, 1028, v - 8192);
    *(fvec4*)HIp(base, 16 * i + 10, v) = val;
  }
}

// ---------------- kron block (both layers) ----------------
// Per row b: X[k][j] = in[b][64k+j] (post BN+relu, bf16).
//   V  = X * RW      (M=k, N=r, K=j)   wave w owns k-tile w
//   Z^T= V^T * LW    (M=r, N=o, K=k)   wave w owns o-tile w
// out feature = o*64 + r;  Z^T lane (m,g) reg e = Zt[rt*16+g*4+e][w*16+m]
// LAYER==1: in = x(f32)+BN0; out: t1 bf16 at slot-low-half; bn1 partials.
// LAYER==2: in = t1(bf16, own slots)+BN1; out: float x + Z + C2T (full slots).
template <int LAYER>
__global__ __launch_bounds__(256) void k_kron(const float* __restrict__ x,
                                              const float* __restrict__ lw,
                                              const float* __restrict__ rw,
                                              char* base) {
  __shared__ unsigned short vt[2][64 * 64];   // V^T bf16, XOR-swizzled, double-buffered
  const int tid = threadIdx.x, bid = blockIdx.x;
  const int w = tid >> 6, l = tid & 63, m = l & 15, g = l >> 4;
  const int r0 = bid * RPB;

  // RW B-frags: frw[rt][ks][i] = RW[ks*32+g*8+i][rt*16+m]
  bfrag8 frw[4][2];
#pragma unroll
  for (int rt = 0; rt < 4; ++rt)
#pragma unroll
    for (int ks = 0; ks < 2; ++ks)
#pragma unroll
      for (int i = 0; i < 8; ++i)
        frw[rt][ks][i] = (short)f2bf_bits(rw[(ks * 32 + g * 8 + i) * 64 + rt * 16 + m]);

  // LW B-frags (o-tile w): flw[ks][i] = LW[ks*32+g*8+i][w*16+m]
  bfrag8 flw[2];
#pragma unroll
  for (int ks = 0; ks < 2; ++ks)
#pragma unroll
    for (int i = 0; i < 8; ++i)
      flw[ks][i] = (short)f2bf_bits(lw[(ks * 32 + g * 8 + i) * 64 + w * 16 + m]);

  // bias: cb[rt][e] = CT[r=rt*16+g*4+e][o=w*16+m]
  fvec4 cb[4];
#pragma unroll
  for (int rt = 0; rt < 4; ++rt)
#pragma unroll
    for (int e = 0; e < 4; ++e) {
      int v = (rt * 16 + g * 4 + e) * 64 + w * 16 + m;
      cb[rt][e] = (LAYER == 1) ? *HIp(base, 1036, v)
                               : *HIp(base, 16 * bid + 10, 8192 + v);
    }

  // BN scale/shift for this lane's A-frag features
  float sc[2][8], sh[2][8];
#pragma unroll
  for (int ks = 0; ks < 2; ++ks)
#pragma unroll
    for (int i = 0; i < 8; ++i) {
      int f = (w * 16 + m) * 64 + ks * 32 + g * 8 + i;
      if (LAYER == 1) {
        sc[ks][i] = *HIp(base, 1032, f);
        sh[ks][i] = *HIp(base, 1032, 4096 + f);
      } else {
        sc[ks][i] = *HIp(base, 16 * bid + 10, f);
        sh[ks][i] = *HIp(base, 16 * bid + 10, 4096 + f);
      }
    }

  __syncthreads();   // all prologue scratch reads complete before any slot write

  fvec4 s1[4], q1[4];
#pragma unroll
  for (int rt = 0; rt < 4; ++rt) { s1[rt] = fvec4{0.f,0.f,0.f,0.f}; q1[rt] = s1[rt]; }

  for (int rr = 0; rr < RPB; ++rr) {
    const int b = r0 + rr;
    const int buf = rr & 1;

    // ---- A-frags: load, BN, relu, -> bf16 ----
    bfrag8 fa[2];
    if constexpr (LAYER == 1) {
      const fvec4* px = (const fvec4*)(x + (size_t)b * NFEAT + (w * 16 + m) * 64);
#pragma unroll
      for (int ks = 0; ks < 2; ++ks) {
        fvec4 v0 = px[ks * 8 + g * 2];
        fvec4 v1 = px[ks * 8 + g * 2 + 1];
        float yv[8] = {v0[0], v0[1], v0[2], v0[3], v1[0], v1[1], v1[2], v1[3]};
#pragma unroll
        for (int i = 0; i < 8; ++i) {
          float y = fmaxf(yv[i] * sc[ks][i] + sh[ks][i], 0.f);
          fa[ks][i] = (short)f2bf_bits(y);
        }
      }
    } else {
      // t1 row b lives at slot b's LOW half (bytes b*SLOT + feature*2)
      const usvec8* pt = (const usvec8*)(base + (size_t)b * SLOT + (w * 16 + m) * 128);
#pragma unroll
      for (int ks = 0; ks < 2; ++ks) {
        usvec8 tv = pt[ks * 4 + g];
#pragma unroll
        for (int i = 0; i < 8; ++i) {
          float y = fmaxf(bf2f(tv[i]) * sc[ks][i] + sh[ks][i], 0.f);
          fa[ks][i] = (short)f2bf_bits(y);
        }
      }
    }

    // ---- matmul1: V = X*RW ; write V^T (bf16, swizzled) to LDS ----
#pragma unroll
    for (int rt = 0; rt < 4; ++rt) {
      fvec4 va = fvec4{0.f,0.f,0.f,0.f};
      va = __builtin_amdgcn_mfma_f32_16x16x32_bf16(fa[0], frw[rt][0], va, 0, 0, 0);
      va = __builtin_amdgcn_mfma_f32_16x16x32_bf16(fa[1], frw[rt][1], va, 0, 0, 0);
      // lane holds V[w*16+g*4+e][rt*16+m] -> V^T row ridx=rt*16+m, k0=w*16+g*4
      int ridx = rt * 16 + m;
      int chunk = 2 * w + (g >> 1);                 // (byte_in_row=32w+8g)>>4
      int byte = ridx * 128 + ((chunk ^ (ridx & 7)) << 4) + ((g & 1) * 8);
      usvec4 pk;
#pragma unroll
      for (int e = 0; e < 4; ++e) pk[e] = f2bf_bits(va[e]);
      *(usvec4*)((char*)(&vt[buf][0]) + byte) = pk;
    }
    __syncthreads();

    // ---- matmul2: Z^T = V^T * LW (o-tile = w) ----
    fvec4 za[4];
#pragma unroll
    for (int rt = 0; rt < 4; ++rt) za[rt] = fvec4{0.f,0.f,0.f,0.f};
#pragma unroll
    for (int ks = 0; ks < 2; ++ks) {
#pragma unroll
      for (int rt = 0; rt < 4; ++rt) {
        int ridx = rt * 16 + m;
        int byte = ridx * 128 + (((ks * 4 + g) ^ (ridx & 7)) << 4);
        bfrag8 av = *(const bfrag8*)((const char*)(&vt[buf][0]) + byte);
        za[rt] = __builtin_amdgcn_mfma_f32_16x16x32_bf16(av, flw[ks], za[rt], 0, 0, 0);
      }
    }

    // ---- epilogue ----
    if constexpr (LAYER == 1) {
#pragma unroll
      for (int rt = 0; rt < 4; ++rt) {
        fvec4 z = za[rt] + cb[rt];
        s1[rt] += z; q1[rt] += z * z;
        usvec4 pk;
#pragma unroll
        for (int e = 0; e < 4; ++e) pk[e] = f2bf_bits(z[e]);
        *(usvec4*)(base + (size_t)b * SLOT +
                   ((w * 16 + m) * 64 + rt * 16 + g * 4) * 2) = pk;
      }
    } else {
      const fvec4* pin  = (const fvec4*)(x + (size_t)b * NFEAT);
      fvec4*       pout = (fvec4*)(base + (size_t)b * SLOT);
#pragma unroll
      for (int rt = 0; rt < 4; ++rt) {
        int fi = ((w * 16 + m) * 64 + rt * 16 + g * 4) >> 2;
        fvec4 iv = pin[fi];
        pout[fi] = iv + za[rt] + cb[rt];
      }
    }
  }

  if constexpr (LAYER == 1) {
    // bn1 partials: each feature owned by exactly one thread -> plain writes
#pragma unroll
    for (int rt = 0; rt < 4; ++rt) {
      int vf = (w * 16 + m) * 64 + rt * 16 + g * 4;
      *(fvec4*)HIp(base, 16 * bid, vf)        = s1[rt];
      *(fvec4*)HIp(base, 16 * bid, 4096 + vf) = q1[rt];
    }
  }
}

extern "C" void kernel_launch(void* const* d_in, const int* in_sizes, int n_in,
                              void* d_out, int out_size, void* d_ws, size_t ws_size,
                              hipStream_t stream) {
  (void)in_sizes; (void)n_in; (void)out_size; (void)d_ws; (void)ws_size;
  const float* x    = (const float*)d_in[0];
  const float* g0   = (const float*)d_in[1];
  const float* b0   = (const float*)d_in[2];
  const float* g1   = (const float*)d_in[3];
  const float* b1   = (const float*)d_in[4];
  const float* k1lw = (const float*)d_in[5];
  const float* k1lb = (const float*)d_in[6];
  const float* k1rw = (const float*)d_in[7];
  const float* k1rb = (const float*)d_in[8];
  const float* k2lw = (const float*)d_in[9];
  const float* k2lb = (const float*)d_in[10];
  const float* k2rw = (const float*)d_in[11];
  const float* k2rb = (const float*)d_in[12];
  char* base = (char*)d_out;

  k_bn0part<<<256, 256, 0, stream>>>(x, base);
  k_prep0<<<48, 256, 0, stream>>>(g0, b0, k1lb, k1rw, k1rb, k2lb, k2rw, k2rb, base);
  k_kron<1><<<NROWS / RPB, 256, 0, stream>>>(x, k1lw, k1rw, base);
  k_prep2a<<<16, 256, 0, stream>>>(g1, b1, base);
  k_prep2b<<<1024, 256, 0, stream>>>(base);
  k_kron<2><<<NROWS / RPB, 256, 0, stream>>>(x, k2lw, k2rw, base);
}

// Round 3
// 427.007 us; speedup vs baseline: 1.1891x; 1.1891x over previous
//
#include <hip/hip_runtime.h>

#define NROWS 16384
#define NFEAT 4096
#define SLOT  16384       // bytes per output-row slot in d_out

typedef __attribute__((ext_vector_type(8))) short          bfrag8;  // 8 x bf16
typedef __attribute__((ext_vector_type(4))) float          fvec4;
typedef __attribute__((ext_vector_type(4))) unsigned short usvec4;
typedef __attribute__((ext_vector_type(8))) unsigned short usvec8;

// ---- scratch lives in the HIGH half (bytes 8192..16384) of d_out row slots ----
//   float v of region at `row`  ->  byte (row + v/2048)*SLOT + 8192 + (v%2048)*4
// Regions:
//   bn0 partials   : rows 4p, p<1024 (8192 floats each)     [bn0part W -> red R]
//   scale0|shift0  : row 4100 (8192)                         [red W -> kron1 R]
//   C1T            : row 4116 (4096)                         [prepC W -> kron1 R]
//   C2T staging    : row 4118 (4096)                         [prepC W -> prep2b R]
//   scale1|shift1  : row 4132 (8192, staging)                [red W -> prep2b R]
//   bn1 partials   : rows 8i, i<2048 (8192 each)             [kron1 W -> red R]
//   kron2 replicas : rows 16i+10 (12288 each)                [prep2b W -> kron2(i) R]
// Coloring: kron1 partial writes hit rows ==0..3 (mod 8) high; replicas ==10..15
// (mod 16); all shared/staging rows are ==4..7 (mod 16) -> disjoint per stage.

__device__ __forceinline__ float* HIp(char* base, int row, int v) {
  return (float*)(base + (size_t)(row + (v >> 11)) * SLOT + 8192 + ((size_t)(v & 2047) << 2));
}

__device__ __forceinline__ unsigned short f2bf_bits(float f) {
  unsigned u = __builtin_bit_cast(unsigned, f);
  u += 0x7FFFu + ((u >> 16) & 1u);          // round-to-nearest-even
  return (unsigned short)(u >> 16);
}
__device__ __forceinline__ float bf2f(unsigned short b) {
  return __builtin_bit_cast(float, ((unsigned)b) << 16);
}

// ---------------- BN0 partial sums ----------------
__global__ __launch_bounds__(256) void k_bn0part(const float* __restrict__ x,
                                                 char* base) {
  const int t = threadIdx.x, p = blockIdx.x;          // 1024 blocks, 16 rows each
  fvec4 s[4], sq[4];
#pragma unroll
  for (int q = 0; q < 4; ++q) { s[q] = fvec4{0.f,0.f,0.f,0.f}; sq[q] = s[q]; }
  for (int r = p * 16; r < p * 16 + 16; ++r) {
    const fvec4* row = (const fvec4*)(x + (size_t)r * NFEAT);
#pragma unroll
    for (int q = 0; q < 4; ++q) {
      fvec4 v = row[t + 256 * q];
      s[q] += v; sq[q] += v * v;
    }
  }
#pragma unroll
  for (int q = 0; q < 4; ++q) {
    int f0 = (t + 256 * q) * 4;
    *(fvec4*)HIp(base, 4 * p, f0)        = s[q];
    *(fvec4*)HIp(base, 4 * p, 4096 + f0) = sq[q];
  }
}

// ---------------- generic BN reduce: partials -> scale|shift ----------------
__global__ __launch_bounds__(256) void k_red(char* base, int nsets, int stride,
                                             const float* __restrict__ g,
                                             const float* __restrict__ bta,
                                             int outrow) {
  __shared__ fvec4 red[16][16][2];                    // [chunk][col][sum/sq]
  const int t = threadIdx.x, j = blockIdx.x;          // 64 blocks, 64 features each
  const int fc = t & 15, c = t >> 4;
  const int v = j * 64 + fc * 4;
  fvec4 s = fvec4{0.f,0.f,0.f,0.f}, q = s;
  for (int i = c; i < nsets; i += 16) {
    s += *(fvec4*)HIp(base, stride * i, v);
    q += *(fvec4*)HIp(base, stride * i, 4096 + v);
  }
  red[c][fc][0] = s; red[c][fc][1] = q;
  __syncthreads();
  if (c == 0) {
    fvec4 S = red[0][fc][0], Q = red[0][fc][1];
#pragma unroll
    for (int k = 1; k < 16; ++k) { S += red[k][fc][0]; Q += red[k][fc][1]; }
    fvec4 SC, SH;
    const float inv = 1.0f / NROWS;
#pragma unroll
    for (int e = 0; e < 4; ++e) {
      float mean = S[e] * inv;
      float var  = Q[e] * inv - mean * mean;
      float scv  = g[v + e] * rsqrtf(var + 1e-3f);
      SC[e] = scv; SH[e] = bta[v + e] - mean * scv;
    }
    *(fvec4*)HIp(base, outrow, v)        = SC;
    *(fvec4*)HIp(base, outrow, 4096 + v) = SH;
  }
}

// ---------------- prepC: C1T (row 4116) + C2T staging (row 4118) ----------------
__global__ __launch_bounds__(256) void k_prepC(const float* __restrict__ lb1,
                                               const float* __restrict__ rw1,
                                               const float* __restrict__ rb1,
                                               const float* __restrict__ lb2,
                                               const float* __restrict__ rw2,
                                               const float* __restrict__ rb2,
                                               char* base) {
  const int idx  = (blockIdx.x & 15) * 256 + threadIdx.x;   // 0..4095
  const int part = blockIdx.x >> 4;                          // 0 -> C1T, 1 -> C2T
  const float* lb = part ? lb2 : lb1;
  const float* rw = part ? rw2 : rw1;
  const float* rb = part ? rb2 : rb1;
  int r = idx >> 6, o = idx & 63;
  float acc = rb[o * 64 + r];
  for (int j = 0; j < 64; ++j) acc += lb[o * 64 + j] * rw[j * 64 + r];
  *HIp(base, part ? 4118 : 4116, idx) = acc;                 // CT[r][o]
}

// ---------------- prep2b: replicate scale1|shift1|C2T into each kron2 block's rows ----------------
__global__ __launch_bounds__(256) void k_prep2b(char* base) {
  const int t = threadIdx.x, i = blockIdx.x;                 // 1024 blocks
#pragma unroll
  for (int c = 0; c < 12; ++c) {
    int v = (t + 256 * c) * 4;                               // 0..12284
    fvec4 val = (v < 8192) ? *(fvec4*)HIp(base, 4132, v)
                           : *(fvec4*)HIp(base, 4118, v - 8192);
    *(fvec4*)HIp(base, 16 * i + 10, v) = val;
  }
}

// ---------------- kron block (both layers), software-pipelined ----------------
// Per row b: X[k][j] = in[b][64k+j] (post BN+relu, bf16).
//   V  = X * RW      (M=k, N=r, K=j)   wave w owns k-tile w
//   Z^T= V^T * LW    (M=r, N=o, K=k)   wave w owns o-tile w
// LAYER==1 (RPBN=8):  in = x(f32)+BN0; out: t1 bf16 at slot-low-half; bn1 partials row 8*bid.
// LAYER==2 (RPBN=16): in = t1(bf16)+BN1; out: float x + Z + C2T (full slots).
template <int LAYER, int RPBN>
__global__ __launch_bounds__(256) void k_kron(const float* __restrict__ x,
                                              const float* __restrict__ lw,
                                              const float* __restrict__ rw,
                                              char* base) {
  __shared__ unsigned short vt[2][64 * 64];   // V^T bf16, XOR-swizzled, double-buffered
  const int tid = threadIdx.x, bid = blockIdx.x;
  const int w = tid >> 6, l = tid & 63, m = l & 15, g = l >> 4;
  const int r0 = bid * RPBN;

  // RW B-frags: frw[rt][ks][i] = RW[ks*32+g*8+i][rt*16+m]
  bfrag8 frw[4][2];
#pragma unroll
  for (int rt = 0; rt < 4; ++rt)
#pragma unroll
    for (int ks = 0; ks < 2; ++ks)
#pragma unroll
      for (int i = 0; i < 8; ++i)
        frw[rt][ks][i] = (short)f2bf_bits(rw[(ks * 32 + g * 8 + i) * 64 + rt * 16 + m]);

  // LW B-frags (o-tile w): flw[ks][i] = LW[ks*32+g*8+i][w*16+m]
  bfrag8 flw[2];
#pragma unroll
  for (int ks = 0; ks < 2; ++ks)
#pragma unroll
    for (int i = 0; i < 8; ++i)
      flw[ks][i] = (short)f2bf_bits(lw[(ks * 32 + g * 8 + i) * 64 + w * 16 + m]);

  // bias: cb[rt][e] = CT[r=rt*16+g*4+e][o=w*16+m]
  fvec4 cb[4];
#pragma unroll
  for (int rt = 0; rt < 4; ++rt)
#pragma unroll
    for (int e = 0; e < 4; ++e) {
      int v = (rt * 16 + g * 4 + e) * 64 + w * 16 + m;
      cb[rt][e] = (LAYER == 1) ? *HIp(base, 4116, v)
                               : *HIp(base, 16 * bid + 10, 8192 + v);
    }

  // BN scale/shift for this lane's A-frag features
  float sc[2][8], sh[2][8];
#pragma unroll
  for (int ks = 0; ks < 2; ++ks)
#pragma unroll
    for (int i = 0; i < 8; ++i) {
      int f = (w * 16 + m) * 64 + ks * 32 + g * 8 + i;
      if (LAYER == 1) {
        sc[ks][i] = *HIp(base, 4100, f);
        sh[ks][i] = *HIp(base, 4100, 4096 + f);
      } else {
        sc[ks][i] = *HIp(base, 16 * bid + 10, f);
        sh[ks][i] = *HIp(base, 16 * bid + 10, 4096 + f);
      }
    }

  if constexpr (LAYER == 2) __syncthreads();  // replica reads done before any slot write

  fvec4 s1[4], q1[4];
#pragma unroll
  for (int rt = 0; rt < 4; ++rt) { s1[rt] = fvec4{0.f,0.f,0.f,0.f}; q1[rt] = s1[rt]; }

  // software-pipeline prefetch buffers (statically indexed under full unroll)
  fvec4  pfx[2][4];   // layer1 A-source
  usvec8 pft[2][2];   // layer2 A-source (t1)
  fvec4  pfr[2][4];   // layer2 residual

  if constexpr (LAYER == 1) {
    const fvec4* px = (const fvec4*)(x + (size_t)r0 * NFEAT + (w * 16 + m) * 64);
    pfx[0][0] = px[g * 2];     pfx[0][1] = px[g * 2 + 1];
    pfx[0][2] = px[8 + g * 2]; pfx[0][3] = px[8 + g * 2 + 1];
  } else {
    const usvec8* pt = (const usvec8*)(base + (size_t)r0 * SLOT + (w * 16 + m) * 128);
    pft[0][0] = pt[g]; pft[0][1] = pt[4 + g];
    const fvec4* pin = (const fvec4*)(x + (size_t)r0 * NFEAT);
#pragma unroll
    for (int rt = 0; rt < 4; ++rt)
      pfr[0][rt] = pin[((w * 16 + m) * 64 + rt * 16 + g * 4) >> 2];
  }

#pragma unroll
  for (int rr = 0; rr < RPBN; ++rr) {
    const int b = r0 + rr;
    const int cur = rr & 1, nxt = cur ^ 1;

    // ---- issue next row's loads (stay in flight across the lgkm-only barrier) ----
    if (rr + 1 < RPBN) {
      if constexpr (LAYER == 1) {
        const fvec4* px = (const fvec4*)(x + (size_t)(b + 1) * NFEAT + (w * 16 + m) * 64);
        pfx[nxt][0] = px[g * 2];     pfx[nxt][1] = px[g * 2 + 1];
        pfx[nxt][2] = px[8 + g * 2]; pfx[nxt][3] = px[8 + g * 2 + 1];
      } else {
        const usvec8* pt = (const usvec8*)(base + (size_t)(b + 1) * SLOT + (w * 16 + m) * 128);
        pft[nxt][0] = pt[g]; pft[nxt][1] = pt[4 + g];
        const fvec4* pin = (const fvec4*)(x + (size_t)(b + 1) * NFEAT);
#pragma unroll
        for (int rt = 0; rt < 4; ++rt)
          pfr[nxt][rt] = pin[((w * 16 + m) * 64 + rt * 16 + g * 4) >> 2];
      }
    }

    // ---- A-frags: BN + relu + pack (consumes prefetched regs; counted vmcnt) ----
    bfrag8 fa[2];
    if constexpr (LAYER == 1) {
#pragma unroll
      for (int ks = 0; ks < 2; ++ks) {
        fvec4 v0 = pfx[cur][ks * 2], v1 = pfx[cur][ks * 2 + 1];
        float yv[8] = {v0[0], v0[1], v0[2], v0[3], v1[0], v1[1], v1[2], v1[3]};
#pragma unroll
        for (int i = 0; i < 8; ++i) {
          float y = fmaxf(yv[i] * sc[ks][i] + sh[ks][i], 0.f);
          fa[ks][i] = (short)f2bf_bits(y);
        }
      }
    } else {
#pragma unroll
      for (int ks = 0; ks < 2; ++ks) {
        usvec8 tv = pft[cur][ks];
#pragma unroll
        for (int i = 0; i < 8; ++i) {
          float y = fmaxf(bf2f(tv[i]) * sc[ks][i] + sh[ks][i], 0.f);
          fa[ks][i] = (short)f2bf_bits(y);
        }
      }
    }

    // ---- matmul1: V = X*RW ; write V^T (bf16, swizzled) to LDS ----
#pragma unroll
    for (int rt = 0; rt < 4; ++rt) {
      fvec4 va = fvec4{0.f,0.f,0.f,0.f};
      va = __builtin_amdgcn_mfma_f32_16x16x32_bf16(fa[0], frw[rt][0], va, 0, 0, 0);
      va = __builtin_amdgcn_mfma_f32_16x16x32_bf16(fa[1], frw[rt][1], va, 0, 0, 0);
      int ridx = rt * 16 + m;
      int chunk = 2 * w + (g >> 1);
      int byte = ridx * 128 + ((chunk ^ (ridx & 7)) << 4) + ((g & 1) * 8);
      usvec4 pk;
#pragma unroll
      for (int e = 0; e < 4; ++e) pk[e] = f2bf_bits(va[e]);
      *(usvec4*)((char*)(&vt[cur][0]) + byte) = pk;
    }

    // LDS-only barrier: drains ds ops, leaves global prefetch/stores in flight
    asm volatile("s_waitcnt lgkmcnt(0)\n\ts_barrier" ::: "memory");

    // ---- matmul2: Z^T = V^T * LW (o-tile = w) ----
    fvec4 za[4];
#pragma unroll
    for (int rt = 0; rt < 4; ++rt) za[rt] = fvec4{0.f,0.f,0.f,0.f};
#pragma unroll
    for (int ks = 0; ks < 2; ++ks) {
#pragma unroll
      for (int rt = 0; rt < 4; ++rt) {
        int ridx = rt * 16 + m;
        int byte = ridx * 128 + (((ks * 4 + g) ^ (ridx & 7)) << 4);
        bfrag8 av = *(const bfrag8*)((const char*)(&vt[cur][0]) + byte);
        za[rt] = __builtin_amdgcn_mfma_f32_16x16x32_bf16(av, flw[ks], za[rt], 0, 0, 0);
      }
    }

    // ---- epilogue ----
    if constexpr (LAYER == 1) {
#pragma unroll
      for (int rt = 0; rt < 4; ++rt) {
        fvec4 z = za[rt] + cb[rt];
        s1[rt] += z; q1[rt] += z * z;
        usvec4 pk;
#pragma unroll
        for (int e = 0; e < 4; ++e) pk[e] = f2bf_bits(z[e]);
        *(usvec4*)(base + (size_t)b * SLOT +
                   ((w * 16 + m) * 64 + rt * 16 + g * 4) * 2) = pk;
      }
    } else {
      fvec4* pout = (fvec4*)(base + (size_t)b * SLOT);
#pragma unroll
      for (int rt = 0; rt < 4; ++rt) {
        int fi = ((w * 16 + m) * 64 + rt * 16 + g * 4) >> 2;
        pout[fi] = pfr[cur][rt] + za[rt] + cb[rt];
      }
    }
  }

  if constexpr (LAYER == 1) {
    // bn1 partials: each feature owned by exactly one thread -> plain writes
#pragma unroll
    for (int rt = 0; rt < 4; ++rt) {
      int vf = (w * 16 + m) * 64 + rt * 16 + g * 4;
      *(fvec4*)HIp(base, 8 * bid, vf)        = s1[rt];
      *(fvec4*)HIp(base, 8 * bid, 4096 + vf) = q1[rt];
    }
  }
}

extern "C" void kernel_launch(void* const* d_in, const int* in_sizes, int n_in,
                              void* d_out, int out_size, void* d_ws, size_t ws_size,
                              hipStream_t stream) {
  (void)in_sizes; (void)n_in; (void)out_size; (void)d_ws; (void)ws_size;
  const float* x    = (const float*)d_in[0];
  const float* g0   = (const float*)d_in[1];
  const float* b0   = (const float*)d_in[2];
  const float* g1   = (const float*)d_in[3];
  const float* b1   = (const float*)d_in[4];
  const float* k1lw = (const float*)d_in[5];
  const float* k1lb = (const float*)d_in[6];
  const float* k1rw = (const float*)d_in[7];
  const float* k1rb = (const float*)d_in[8];
  const float* k2lw = (const float*)d_in[9];
  const float* k2lb = (const float*)d_in[10];
  const float* k2rw = (const float*)d_in[11];
  const float* k2rb = (const float*)d_in[12];
  char* base = (char*)d_out;

  k_bn0part<<<1024, 256, 0, stream>>>(x, base);
  k_red<<<64, 256, 0, stream>>>(base, 1024, 4, g0, b0, 4100);
  k_prepC<<<32, 256, 0, stream>>>(k1lb, k1rw, k1rb, k2lb, k2rw, k2rb, base);
  k_kron<1, 8><<<NROWS / 8, 256, 0, stream>>>(x, k1lw, k1rw, base);
  k_red<<<64, 256, 0, stream>>>(base, 2048, 8, g1, b1, 4132);
  k_prep2b<<<1024, 256, 0, stream>>>(base);
  k_kron<2, 16><<<NROWS / 16, 256, 0, stream>>>(x, k2lw, k2rw, base);
}

// Round 4
// 409.643 us; speedup vs baseline: 1.2396x; 1.0424x over previous
//
#include <hip/hip_runtime.h>

#define NROWS 16384
#define NFEAT 4096
#define SLOT  16384       // bytes per output-row slot in d_out

typedef __attribute__((ext_vector_type(8))) short          bfrag8;  // 8 x bf16
typedef __attribute__((ext_vector_type(4))) float          fvec4;
typedef __attribute__((ext_vector_type(4))) unsigned short usvec4;
typedef __attribute__((ext_vector_type(8))) unsigned short usvec8;

// ---- scratch lives in the HIGH half (bytes 8192..16384) of d_out row slots ----
// f32 regions:  float v at `row`  ->  byte (row + v/2048)*SLOT + 8192 + (v%2048)*4
//   scale0|shift0 : rows 4100-4103 (8192 f)   [red W -> kron1 R (shared)]
//   C1N[o][r]     : rows 4116-4117 (4096 f)   [prepC W -> kron1 R (shared)]
//   C2N[o][r] stg : rows 4118-4119 (4096 f)   [prepC W -> prep2b R]
//   scale1|shift1 : rows 4132-4135 (8192 f)   [red W -> prep2b R]
// bf16 regions: bf16 u at `row`  ->  byte row*SLOT + 8192 + u*2  (u<4096/row)
//   bn0 partials  : row p, p<1024 (8192 bf16 = 1 row)   [bn0part W -> red R]
//   bn1 partials  : row 8i, i<2048 (8192 bf16 = 1 row)  [kron1 W -> red R]
//   kron2 replica : rows 16i+10,11,12 (12288 bf16)      [prep2b W -> kron2(i) R]
// Coloring: bn1 partial rows ==0 (mod 8); replica rows ==10,11,12 (mod 16);
// shared/staging rows ==4..7 (mod 16) -> disjoint per pipeline stage.
// bn0 partial rows 0..1023 are consumed by red0 before kron1 overwrites them.

__device__ __forceinline__ float* HIp(char* base, int row, int v) {
  return (float*)(base + (size_t)(row + (v >> 11)) * SLOT + 8192 + ((size_t)(v & 2047) << 2));
}
__device__ __forceinline__ char* HBp(char* base, int row, int u) {
  return base + (size_t)row * SLOT + 8192 + ((size_t)u << 1);
}

__device__ __forceinline__ unsigned short f2bf_bits(float f) {
  unsigned u = __builtin_bit_cast(unsigned, f);
  u += 0x7FFFu + ((u >> 16) & 1u);          // round-to-nearest-even
  return (unsigned short)(u >> 16);
}
__device__ __forceinline__ float bf2f(unsigned short b) {
  return __builtin_bit_cast(float, ((unsigned)b) << 16);
}
__device__ __forceinline__ usvec4 pack4(fvec4 a) {
  usvec4 p;
#pragma unroll
  for (int e = 0; e < 4; ++e) p[e] = f2bf_bits(a[e]);
  return p;
}
__device__ __forceinline__ fvec4 unpack4(usvec4 p) {
  return fvec4{bf2f(p[0]), bf2f(p[1]), bf2f(p[2]), bf2f(p[3])};
}

// ---------------- BN0 partial sums (bf16 spill) ----------------
__global__ __launch_bounds__(256) void k_bn0part(const float* __restrict__ x,
                                                 char* base) {
  const int t = threadIdx.x, p = blockIdx.x;          // 1024 blocks, 16 rows each
  fvec4 s[4], sq[4];
#pragma unroll
  for (int q = 0; q < 4; ++q) { s[q] = fvec4{0.f,0.f,0.f,0.f}; sq[q] = s[q]; }
  for (int r = p * 16; r < p * 16 + 16; ++r) {
    const fvec4* row = (const fvec4*)(x + (size_t)r * NFEAT);
#pragma unroll
    for (int q = 0; q < 4; ++q) {
      fvec4 v = row[t + 256 * q];
      s[q] += v; sq[q] += v * v;
    }
  }
#pragma unroll
  for (int q = 0; q < 4; ++q) {
    int f0 = (t + 256 * q) * 4;
    *(usvec4*)HBp(base, p, f0)        = pack4(s[q]);
    *(usvec4*)HBp(base, p, 4096 + f0) = pack4(sq[q]);
  }
}

// ---------------- generic BN reduce: bf16 partials -> f32 scale|shift ----------------
__global__ __launch_bounds__(256) void k_red(char* base, int nsets, int stride,
                                             const float* __restrict__ g,
                                             const float* __restrict__ bta,
                                             int outrow) {
  __shared__ fvec4 red[16][16][2];                    // [chunk][col][sum/sq]
  const int t = threadIdx.x, j = blockIdx.x;          // 64 blocks, 64 features each
  const int fc = t & 15, c = t >> 4;
  const int v = j * 64 + fc * 4;
  fvec4 s = fvec4{0.f,0.f,0.f,0.f}, q = s;
  for (int i = c; i < nsets; i += 16) {
    s += unpack4(*(usvec4*)HBp(base, stride * i, v));
    q += unpack4(*(usvec4*)HBp(base, stride * i, 4096 + v));
  }
  red[c][fc][0] = s; red[c][fc][1] = q;
  __syncthreads();
  if (c == 0) {
    fvec4 S = red[0][fc][0], Q = red[0][fc][1];
#pragma unroll
    for (int k = 1; k < 16; ++k) { S += red[k][fc][0]; Q += red[k][fc][1]; }
    fvec4 SC, SH;
    const float inv = 1.0f / NROWS;
#pragma unroll
    for (int e = 0; e < 4; ++e) {
      float mean = S[e] * inv;
      float var  = Q[e] * inv - mean * mean;
      float scv  = g[v + e] * rsqrtf(var + 1e-3f);
      SC[e] = scv; SH[e] = bta[v + e] - mean * scv;
    }
    *(fvec4*)HIp(base, outrow, v)        = SC;
    *(fvec4*)HIp(base, outrow, 4096 + v) = SH;
  }
}

// ---------------- prepC: C1N (row 4116) + C2N staging (row 4118), stored [o][r] ----------------
__global__ __launch_bounds__(256) void k_prepC(const float* __restrict__ lb1,
                                               const float* __restrict__ rw1,
                                               const float* __restrict__ rb1,
                                               const float* __restrict__ lb2,
                                               const float* __restrict__ rw2,
                                               const float* __restrict__ rb2,
                                               char* base) {
  const int idx  = (blockIdx.x & 15) * 256 + threadIdx.x;   // 0..4095
  const int part = blockIdx.x >> 4;                          // 0 -> C1, 1 -> C2
  const float* lb = part ? lb2 : lb1;
  const float* rw = part ? rw2 : rw1;
  const float* rb = part ? rb2 : rb1;
  int r = idx >> 6, o = idx & 63;
  float acc = rb[o * 64 + r];
  for (int j = 0; j < 64; ++j) acc += lb[o * 64 + j] * rw[j * 64 + r];
  *HIp(base, part ? 4118 : 4116, o * 64 + r) = acc;          // C[o][r]
}

// ---------------- prep2b: bf16 replicas of scale1|shift1|C2N per kron2 block ----------------
__global__ __launch_bounds__(256) void k_prep2b(char* base) {
  const int t = threadIdx.x, i = blockIdx.x;                 // 1024 blocks
  const int r0 = 16 * i + 10;
#pragma unroll
  for (int c = 0; c < 6; ++c) {
    int u = (t + 256 * c) * 8;                               // 0..12280
    fvec4 a  = (u < 8192) ? *(fvec4*)HIp(base, 4132, u)
                          : *(fvec4*)HIp(base, 4118, u - 8192);
    fvec4 b2 = (u < 8192) ? *(fvec4*)HIp(base, 4132, u + 4)
                          : *(fvec4*)HIp(base, 4118, u - 8188);
    usvec8 pk;
#pragma unroll
    for (int e = 0; e < 4; ++e) { pk[e] = f2bf_bits(a[e]); pk[4 + e] = f2bf_bits(b2[e]); }
    int row = r0 + (u >> 12);
    *(usvec8*)(base + (size_t)row * SLOT + 8192 + (size_t)(u & 4095) * 2) = pk;
  }
}

// ---------------- kron block (both layers), software-pipelined ----------------
// Per row b: X[k][j] = in[b][64k+j] (post BN+relu, bf16).
//   V  = X * RW      (M=k, N=r, K=j)   wave w owns k-tile w
//   Z^T= V^T * LW    (M=r, N=o, K=k)   wave w owns o-tile w
// LAYER==1 (RPBN=8):  in = x(f32)+BN0; out: t1 bf16 slot-low; bn1 bf16 partials row 8*bid.
// LAYER==2 (RPBN=16): in = t1(bf16)+BN1; out: float x + Z + C2 (full slots).
template <int LAYER, int RPBN>
__global__ __launch_bounds__(256) void k_kron(const float* __restrict__ x,
                                              const float* __restrict__ lw,
                                              const float* __restrict__ rw,
                                              char* base) {
  __shared__ unsigned short vt[2][64 * 64];   // V^T bf16, XOR-swizzled, double-buffered
  const int tid = threadIdx.x, bid = blockIdx.x;
  const int w = tid >> 6, l = tid & 63, m = l & 15, g = l >> 4;
  const int r0 = bid * RPBN;

  // RW B-frags: frw[rt][ks][i] = RW[ks*32+g*8+i][rt*16+m]
  bfrag8 frw[4][2];
#pragma unroll
  for (int rt = 0; rt < 4; ++rt)
#pragma unroll
    for (int ks = 0; ks < 2; ++ks)
#pragma unroll
      for (int i = 0; i < 8; ++i)
        frw[rt][ks][i] = (short)f2bf_bits(rw[(ks * 32 + g * 8 + i) * 64 + rt * 16 + m]);

  // LW B-frags (o-tile w): flw[ks][i] = LW[ks*32+g*8+i][w*16+m]
  bfrag8 flw[2];
#pragma unroll
  for (int ks = 0; ks < 2; ++ks)
#pragma unroll
    for (int i = 0; i < 8; ++i)
      flw[ks][i] = (short)f2bf_bits(lw[(ks * 32 + g * 8 + i) * 64 + w * 16 + m]);

  // bias: cb[rt] = C[o=w*16+m][r=rt*16+g*4 .. +3]  (vector read, stored [o][r])
  fvec4 cb[4];
  // BN scale/shift for this lane's A-frag features
  float sc[2][8], sh[2][8];

  if constexpr (LAYER == 1) {
#pragma unroll
    for (int rt = 0; rt < 4; ++rt)
      cb[rt] = *(fvec4*)HIp(base, 4116, (w * 16 + m) * 64 + rt * 16 + g * 4);
#pragma unroll
    for (int ks = 0; ks < 2; ++ks) {
      int f = (w * 16 + m) * 64 + ks * 32 + g * 8;
#pragma unroll
      for (int i = 0; i < 8; ++i) {
        sc[ks][i] = *HIp(base, 4100, f + i);
        sh[ks][i] = *HIp(base, 4100, 4096 + f + i);
      }
    }
  } else {
    const int rrow = 16 * bid + 10;
#pragma unroll
    for (int rt = 0; rt < 4; ++rt) {
      int u = 8192 + (w * 16 + m) * 64 + rt * 16 + g * 4;    // row +12
      usvec4 cv = *(const usvec4*)(base + (size_t)(rrow + 2) * SLOT + 8192 +
                                   (size_t)(u & 4095) * 2);
      cb[rt] = unpack4(cv);
    }
#pragma unroll
    for (int ks = 0; ks < 2; ++ks) {
      int f = (w * 16 + m) * 64 + ks * 32 + g * 8;           // f in [0,4096)
      usvec8 sv = *(const usvec8*)(base + (size_t)rrow * SLOT + 8192 + (size_t)f * 2);
      usvec8 hv = *(const usvec8*)(base + (size_t)(rrow + 1) * SLOT + 8192 + (size_t)f * 2);
#pragma unroll
      for (int i = 0; i < 8; ++i) { sc[ks][i] = bf2f(sv[i]); sh[ks][i] = bf2f(hv[i]); }
    }
  }

  if constexpr (LAYER == 2) __syncthreads();  // replica reads done before any slot write

  fvec4 s1[4], q1[4];
#pragma unroll
  for (int rt = 0; rt < 4; ++rt) { s1[rt] = fvec4{0.f,0.f,0.f,0.f}; q1[rt] = s1[rt]; }

  // software-pipeline prefetch buffers (statically indexed under full unroll)
  fvec4  pfx[2][4];   // layer1 A-source
  usvec8 pft[2][2];   // layer2 A-source (t1)
  fvec4  pfr[2][4];   // layer2 residual

  if constexpr (LAYER == 1) {
    const fvec4* px = (const fvec4*)(x + (size_t)r0 * NFEAT + (w * 16 + m) * 64);
    pfx[0][0] = px[g * 2];     pfx[0][1] = px[g * 2 + 1];
    pfx[0][2] = px[8 + g * 2]; pfx[0][3] = px[8 + g * 2 + 1];
  } else {
    const usvec8* pt = (const usvec8*)(base + (size_t)r0 * SLOT + (w * 16 + m) * 128);
    pft[0][0] = pt[g]; pft[0][1] = pt[4 + g];
    const fvec4* pin = (const fvec4*)(x + (size_t)r0 * NFEAT);
#pragma unroll
    for (int rt = 0; rt < 4; ++rt)
      pfr[0][rt] = pin[((w * 16 + m) * 64 + rt * 16 + g * 4) >> 2];
  }

#pragma unroll
  for (int rr = 0; rr < RPBN; ++rr) {
    const int b = r0 + rr;
    const int cur = rr & 1, nxt = cur ^ 1;

    // ---- issue next row's loads (stay in flight across the lgkm-only barrier) ----
    if (rr + 1 < RPBN) {
      if constexpr (LAYER == 1) {
        const fvec4* px = (const fvec4*)(x + (size_t)(b + 1) * NFEAT + (w * 16 + m) * 64);
        pfx[nxt][0] = px[g * 2];     pfx[nxt][1] = px[g * 2 + 1];
        pfx[nxt][2] = px[8 + g * 2]; pfx[nxt][3] = px[8 + g * 2 + 1];
      } else {
        const usvec8* pt = (const usvec8*)(base + (size_t)(b + 1) * SLOT + (w * 16 + m) * 128);
        pft[nxt][0] = pt[g]; pft[nxt][1] = pt[4 + g];
        const fvec4* pin = (const fvec4*)(x + (size_t)(b + 1) * NFEAT);
#pragma unroll
        for (int rt = 0; rt < 4; ++rt)
          pfr[nxt][rt] = pin[((w * 16 + m) * 64 + rt * 16 + g * 4) >> 2];
      }
    }

    // ---- A-frags: BN + relu + pack (consumes prefetched regs) ----
    bfrag8 fa[2];
    if constexpr (LAYER == 1) {
#pragma unroll
      for (int ks = 0; ks < 2; ++ks) {
        fvec4 v0 = pfx[cur][ks * 2], v1 = pfx[cur][ks * 2 + 1];
        float yv[8] = {v0[0], v0[1], v0[2], v0[3], v1[0], v1[1], v1[2], v1[3]};
#pragma unroll
        for (int i = 0; i < 8; ++i) {
          float y = fmaxf(yv[i] * sc[ks][i] + sh[ks][i], 0.f);
          fa[ks][i] = (short)f2bf_bits(y);
        }
      }
    } else {
#pragma unroll
      for (int ks = 0; ks < 2; ++ks) {
        usvec8 tv = pft[cur][ks];
#pragma unroll
        for (int i = 0; i < 8; ++i) {
          float y = fmaxf(bf2f(tv[i]) * sc[ks][i] + sh[ks][i], 0.f);
          fa[ks][i] = (short)f2bf_bits(y);
        }
      }
    }

    // ---- matmul1: V = X*RW ; write V^T (bf16, swizzled) to LDS ----
#pragma unroll
    for (int rt = 0; rt < 4; ++rt) {
      fvec4 va = fvec4{0.f,0.f,0.f,0.f};
      va = __builtin_amdgcn_mfma_f32_16x16x32_bf16(fa[0], frw[rt][0], va, 0, 0, 0);
      va = __builtin_amdgcn_mfma_f32_16x16x32_bf16(fa[1], frw[rt][1], va, 0, 0, 0);
      int ridx = rt * 16 + m;
      int chunk = 2 * w + (g >> 1);
      int byte = ridx * 128 + ((chunk ^ (ridx & 7)) << 4) + ((g & 1) * 8);
      *(usvec4*)((char*)(&vt[cur][0]) + byte) = pack4(va);
    }

    // LDS-only barrier: drains ds ops, leaves global prefetch/stores in flight
    asm volatile("s_waitcnt lgkmcnt(0)\n\ts_barrier" ::: "memory");

    // ---- matmul2: Z^T = V^T * LW (o-tile = w) ----
    fvec4 za[4];
#pragma unroll
    for (int rt = 0; rt < 4; ++rt) za[rt] = fvec4{0.f,0.f,0.f,0.f};
#pragma unroll
    for (int ks = 0; ks < 2; ++ks) {
#pragma unroll
      for (int rt = 0; rt < 4; ++rt) {
        int ridx = rt * 16 + m;
        int byte = ridx * 128 + (((ks * 4 + g) ^ (ridx & 7)) << 4);
        bfrag8 av = *(const bfrag8*)((const char*)(&vt[cur][0]) + byte);
        za[rt] = __builtin_amdgcn_mfma_f32_16x16x32_bf16(av, flw[ks], za[rt], 0, 0, 0);
      }
    }

    // ---- epilogue ----
    if constexpr (LAYER == 1) {
#pragma unroll
      for (int rt = 0; rt < 4; ++rt) {
        fvec4 z = za[rt] + cb[rt];
        s1[rt] += z; q1[rt] += z * z;
        *(usvec4*)(base + (size_t)b * SLOT +
                   ((w * 16 + m) * 64 + rt * 16 + g * 4) * 2) = pack4(z);
      }
    } else {
      fvec4* pout = (fvec4*)(base + (size_t)b * SLOT);
#pragma unroll
      for (int rt = 0; rt < 4; ++rt) {
        int fi = ((w * 16 + m) * 64 + rt * 16 + g * 4) >> 2;
        pout[fi] = pfr[cur][rt] + za[rt] + cb[rt];
      }
    }
  }

  if constexpr (LAYER == 1) {
    // bn1 partials (bf16): each feature owned by exactly one thread -> plain writes
#pragma unroll
    for (int rt = 0; rt < 4; ++rt) {
      int vf = (w * 16 + m) * 64 + rt * 16 + g * 4;
      *(usvec4*)HBp(base, 8 * bid, vf)        = pack4(s1[rt]);
      *(usvec4*)HBp(base, 8 * bid, 4096 + vf) = pack4(q1[rt]);
    }
  }
}

extern "C" void kernel_launch(void* const* d_in, const int* in_sizes, int n_in,
                              void* d_out, int out_size, void* d_ws, size_t ws_size,
                              hipStream_t stream) {
  (void)in_sizes; (void)n_in; (void)out_size; (void)d_ws; (void)ws_size;
  const float* x    = (const float*)d_in[0];
  const float* g0   = (const float*)d_in[1];
  const float* b0   = (const float*)d_in[2];
  const float* g1   = (const float*)d_in[3];
  const float* b1   = (const float*)d_in[4];
  const float* k1lw = (const float*)d_in[5];
  const float* k1lb = (const float*)d_in[6];
  const float* k1rw = (const float*)d_in[7];
  const float* k1rb = (const float*)d_in[8];
  const float* k2lw = (const float*)d_in[9];
  const float* k2lb = (const float*)d_in[10];
  const float* k2rw = (const float*)d_in[11];
  const float* k2rb = (const float*)d_in[12];
  char* base = (char*)d_out;

  k_bn0part<<<1024, 256, 0, stream>>>(x, base);
  k_red<<<64, 256, 0, stream>>>(base, 1024, 1, g0, b0, 4100);
  k_prepC<<<32, 256, 0, stream>>>(k1lb, k1rw, k1rb, k2lb, k2rw, k2rb, base);
  k_kron<1, 8><<<NROWS / 8, 256, 0, stream>>>(x, k1lw, k1rw, base);
  k_red<<<64, 256, 0, stream>>>(base, 2048, 8, g1, b1, 4132);
  k_prep2b<<<1024, 256, 0, stream>>>(base);
  k_kron<2, 16><<<NROWS / 16, 256, 0, stream>>>(x, k2lw, k2rw, base);
}

// Round 5
// 388.876 us; speedup vs baseline: 1.3057x; 1.0534x over previous
//
#include <hip/hip_runtime.h>

#define NROWS 16384
#define NFEAT 4096

typedef __attribute__((ext_vector_type(8))) short          bfrag8;  // 8 x bf16
typedef __attribute__((ext_vector_type(4))) float          fvec4;
typedef __attribute__((ext_vector_type(4))) unsigned short usvec4;
typedef __attribute__((ext_vector_type(8))) unsigned short usvec8;

// ---- d_ws layout (byte offsets; needs ~192 MiB, ws is 1 GiB per harness fill) ----
#define WS_P0   ((size_t)0)            // bn0 partials: 1024 sets x 16 KB (bf16 sum|sumsq)
#define WS_P1   ((size_t)16 << 20)     // bn1 partials: 2048 sets x 16 KB
#define WS_SC0  ((size_t)48 << 20)     // f32[4096] scale0
#define WS_SH0  (WS_SC0 + 16384)       // f32[4096] shift0
#define WS_SC1  (WS_SC0 + 32768)       // f32[4096] scale1
#define WS_SH1  (WS_SC0 + 49152)       // f32[4096] shift1
#define WS_C1   (WS_SC0 + 65536)       // f32[4096] C1[o][r]
#define WS_C2   (WS_SC0 + 81920)       // f32[4096] C2[o][r]
#define WS_T1   ((size_t)64 << 20)     // t1: 16384 rows x 8 KB bf16

__device__ __forceinline__ unsigned short f2bf_bits(float f) {
  unsigned u = __builtin_bit_cast(unsigned, f);
  u += 0x7FFFu + ((u >> 16) & 1u);          // round-to-nearest-even
  return (unsigned short)(u >> 16);
}
__device__ __forceinline__ float bf2f(unsigned short b) {
  return __builtin_bit_cast(float, ((unsigned)b) << 16);
}
__device__ __forceinline__ usvec4 pack4(fvec4 a) {
  usvec4 p;
#pragma unroll
  for (int e = 0; e < 4; ++e) p[e] = f2bf_bits(a[e]);
  return p;
}
__device__ __forceinline__ fvec4 unpack4(usvec4 p) {
  return fvec4{bf2f(p[0]), bf2f(p[1]), bf2f(p[2]), bf2f(p[3])};
}

// ---------------- BN0 partial sums (bf16 spill to ws) ----------------
__global__ __launch_bounds__(256) void k_bn0part(const float* __restrict__ x,
                                                 unsigned short* __restrict__ p0) {
  const int t = threadIdx.x, p = blockIdx.x;          // 1024 blocks, 16 rows each
  fvec4 s[4], sq[4];
#pragma unroll
  for (int q = 0; q < 4; ++q) { s[q] = fvec4{0.f,0.f,0.f,0.f}; sq[q] = s[q]; }
  for (int r = p * 16; r < p * 16 + 16; ++r) {
    const fvec4* row = (const fvec4*)(x + (size_t)r * NFEAT);
#pragma unroll
    for (int q = 0; q < 4; ++q) {
      fvec4 v = row[t + 256 * q];
      s[q] += v; sq[q] += v * v;
    }
  }
#pragma unroll
  for (int q = 0; q < 4; ++q) {
    int f0 = (t + 256 * q) * 4;
    *(usvec4*)(p0 + (size_t)p * 8192 + f0)        = pack4(s[q]);
    *(usvec4*)(p0 + (size_t)p * 8192 + 4096 + f0) = pack4(sq[q]);
  }
}

// ---------------- shared reduce body: bf16 partials -> f32 scale|shift ----------------
__device__ __forceinline__ void red_body(fvec4 (*red)[16][2],
                                         const unsigned short* __restrict__ parts,
                                         int nsets,
                                         const float* __restrict__ g,
                                         const float* __restrict__ bta,
                                         float* __restrict__ sc_out,
                                         float* __restrict__ sh_out, int j) {
  const int t = threadIdx.x;
  const int fc = t & 15, c = t >> 4;
  const int v = j * 64 + fc * 4;
  fvec4 s = fvec4{0.f,0.f,0.f,0.f}, q = s;
  for (int i = c; i < nsets; i += 16) {
    s += unpack4(*(const usvec4*)(parts + (size_t)i * 8192 + v));
    q += unpack4(*(const usvec4*)(parts + (size_t)i * 8192 + 4096 + v));
  }
  red[c][fc][0] = s; red[c][fc][1] = q;
  __syncthreads();
  if (c == 0) {
    fvec4 S = red[0][fc][0], Q = red[0][fc][1];
#pragma unroll
    for (int k = 1; k < 16; ++k) { S += red[k][fc][0]; Q += red[k][fc][1]; }
    fvec4 SC, SH;
    const float inv = 1.0f / NROWS;
#pragma unroll
    for (int e = 0; e < 4; ++e) {
      float mean = S[e] * inv;
      float var  = Q[e] * inv - mean * mean;
      float scv  = g[v + e] * rsqrtf(var + 1e-3f);
      SC[e] = scv; SH[e] = bta[v + e] - mean * scv;
    }
    *(fvec4*)(sc_out + v) = SC;
    *(fvec4*)(sh_out + v) = SH;
  }
}

// ---------------- prep0: red0 (blocks 0-63) + C1/C2 (blocks 64-95) ----------------
__global__ __launch_bounds__(256) void k_prep0(const unsigned short* __restrict__ p0,
                                               const float* __restrict__ g0,
                                               const float* __restrict__ b0,
                                               float* __restrict__ sc0,
                                               float* __restrict__ sh0,
                                               const float* __restrict__ lb1,
                                               const float* __restrict__ rw1,
                                               const float* __restrict__ rb1,
                                               const float* __restrict__ lb2,
                                               const float* __restrict__ rw2,
                                               const float* __restrict__ rb2,
                                               float* __restrict__ c1,
                                               float* __restrict__ c2) {
  __shared__ fvec4 red[16][16][2];
  if (blockIdx.x < 64) {
    red_body(red, p0, 1024, g0, b0, sc0, sh0, blockIdx.x);
  } else {
    const int bb   = blockIdx.x - 64;
    const int idx  = (bb & 15) * 256 + threadIdx.x;   // 0..4095
    const int part = bb >> 4;                          // 0 -> C1, 1 -> C2
    const float* lb = part ? lb2 : lb1;
    const float* rw = part ? rw2 : rw1;
    const float* rb = part ? rb2 : rb1;
    int r = idx >> 6, o = idx & 63;
    float acc = rb[o * 64 + r];
    for (int j = 0; j < 64; ++j) acc += lb[o * 64 + j] * rw[j * 64 + r];
    (part ? c2 : c1)[o * 64 + r] = acc;                // C[o][r]
  }
}

// ---------------- red1: bn1 partials -> scale1|shift1 ----------------
__global__ __launch_bounds__(256) void k_red1(const unsigned short* __restrict__ p1,
                                              const float* __restrict__ g1,
                                              const float* __restrict__ b1,
                                              float* __restrict__ sc1,
                                              float* __restrict__ sh1) {
  __shared__ fvec4 red[16][16][2];
  red_body(red, p1, 2048, g1, b1, sc1, sh1, blockIdx.x);
}

// ---------------- kron block (both layers), software-pipelined ----------------
// Per row b: X[k][j] = in[b][64k+j] (post BN+relu, bf16).
//   V  = X * RW      (M=k, N=r, K=j)   wave w owns k-tile w
//   Z^T= V^T * LW    (M=r, N=o, K=k)   wave w owns o-tile w
// LAYER==1: in = x(f32)+BN0; out: t1 bf16 (ws) + bn1 bf16 partial set bid.
// LAYER==2: in = t1(bf16)+BN1; out: float x + Z + C2 to d_out.
template <int LAYER, int RPBN>
__global__ __launch_bounds__(256) void k_kron(const float* __restrict__ x,
                                              const float* __restrict__ lw,
                                              const float* __restrict__ rw,
                                              const float* __restrict__ scv,
                                              const float* __restrict__ shv,
                                              const float* __restrict__ cn,
                                              unsigned short* __restrict__ t1,
                                              float* __restrict__ outf,
                                              unsigned short* __restrict__ p1) {
  __shared__ unsigned short vt[2][64 * 64];   // V^T bf16, XOR-swizzled, double-buffered
  const int tid = threadIdx.x, bid = blockIdx.x;
  const int w = tid >> 6, l = tid & 63, m = l & 15, g = l >> 4;
  const int r0 = bid * RPBN;

  // RW B-frags: frw[rt][ks][i] = RW[ks*32+g*8+i][rt*16+m]
  bfrag8 frw[4][2];
#pragma unroll
  for (int rt = 0; rt < 4; ++rt)
#pragma unroll
    for (int ks = 0; ks < 2; ++ks)
#pragma unroll
      for (int i = 0; i < 8; ++i)
        frw[rt][ks][i] = (short)f2bf_bits(rw[(ks * 32 + g * 8 + i) * 64 + rt * 16 + m]);

  // LW B-frags (o-tile w): flw[ks][i] = LW[ks*32+g*8+i][w*16+m]
  bfrag8 flw[2];
#pragma unroll
  for (int ks = 0; ks < 2; ++ks)
#pragma unroll
    for (int i = 0; i < 8; ++i)
      flw[ks][i] = (short)f2bf_bits(lw[(ks * 32 + g * 8 + i) * 64 + w * 16 + m]);

  // bias: cb[rt] = C[o=w*16+m][r=rt*16+g*4 .. +3]
  fvec4 cb[4];
#pragma unroll
  for (int rt = 0; rt < 4; ++rt)
    cb[rt] = *(const fvec4*)(cn + (w * 16 + m) * 64 + rt * 16 + g * 4);

  // BN scale/shift for this lane's A-frag features (f32, L2-broadcast)
  float sc[2][8], sh[2][8];
#pragma unroll
  for (int ks = 0; ks < 2; ++ks) {
    int f = (w * 16 + m) * 64 + ks * 32 + g * 8;
    fvec4 a0 = *(const fvec4*)(scv + f), a1 = *(const fvec4*)(scv + f + 4);
    fvec4 h0 = *(const fvec4*)(shv + f), h1 = *(const fvec4*)(shv + f + 4);
#pragma unroll
    for (int e = 0; e < 4; ++e) {
      sc[ks][e] = a0[e]; sc[ks][4 + e] = a1[e];
      sh[ks][e] = h0[e]; sh[ks][4 + e] = h1[e];
    }
  }

  fvec4 s1[4], q1[4];
#pragma unroll
  for (int rt = 0; rt < 4; ++rt) { s1[rt] = fvec4{0.f,0.f,0.f,0.f}; q1[rt] = s1[rt]; }

  // software-pipeline prefetch buffers (statically indexed under full unroll)
  fvec4  pfx[2][4];   // layer1 A-source
  usvec8 pft[2][2];   // layer2 A-source (t1)
  fvec4  pfr[2][4];   // layer2 residual

  if constexpr (LAYER == 1) {
    const fvec4* px = (const fvec4*)(x + (size_t)r0 * NFEAT + (w * 16 + m) * 64);
    pfx[0][0] = px[g * 2];     pfx[0][1] = px[g * 2 + 1];
    pfx[0][2] = px[8 + g * 2]; pfx[0][3] = px[8 + g * 2 + 1];
  } else {
    const usvec8* pt = (const usvec8*)(t1 + (size_t)r0 * NFEAT);
    pft[0][0] = pt[(w * 16 + m) * 8 + g];
    pft[0][1] = pt[(w * 16 + m) * 8 + 4 + g];
    const fvec4* pin = (const fvec4*)(x + (size_t)r0 * NFEAT);
#pragma unroll
    for (int rt = 0; rt < 4; ++rt)
      pfr[0][rt] = pin[((w * 16 + m) * 64 + rt * 16 + g * 4) >> 2];
  }

#pragma unroll
  for (int rr = 0; rr < RPBN; ++rr) {
    const int b = r0 + rr;
    const int cur = rr & 1, nxt = cur ^ 1;

    // ---- issue next row's loads (stay in flight across the lgkm-only barrier) ----
    if (rr + 1 < RPBN) {
      if constexpr (LAYER == 1) {
        const fvec4* px = (const fvec4*)(x + (size_t)(b + 1) * NFEAT + (w * 16 + m) * 64);
        pfx[nxt][0] = px[g * 2];     pfx[nxt][1] = px[g * 2 + 1];
        pfx[nxt][2] = px[8 + g * 2]; pfx[nxt][3] = px[8 + g * 2 + 1];
      } else {
        const usvec8* pt = (const usvec8*)(t1 + (size_t)(b + 1) * NFEAT);
        pft[nxt][0] = pt[(w * 16 + m) * 8 + g];
        pft[nxt][1] = pt[(w * 16 + m) * 8 + 4 + g];
        const fvec4* pin = (const fvec4*)(x + (size_t)(b + 1) * NFEAT);
#pragma unroll
        for (int rt = 0; rt < 4; ++rt)
          pfr[nxt][rt] = pin[((w * 16 + m) * 64 + rt * 16 + g * 4) >> 2];
      }
    }

    // ---- A-frags: BN + relu + pack (consumes prefetched regs) ----
    bfrag8 fa[2];
    if constexpr (LAYER == 1) {
#pragma unroll
      for (int ks = 0; ks < 2; ++ks) {
        fvec4 v0 = pfx[cur][ks * 2], v1 = pfx[cur][ks * 2 + 1];
        float yv[8] = {v0[0], v0[1], v0[2], v0[3], v1[0], v1[1], v1[2], v1[3]};
#pragma unroll
        for (int i = 0; i < 8; ++i) {
          float y = fmaxf(yv[i] * sc[ks][i] + sh[ks][i], 0.f);
          fa[ks][i] = (short)f2bf_bits(y);
        }
      }
    } else {
#pragma unroll
      for (int ks = 0; ks < 2; ++ks) {
        usvec8 tv = pft[cur][ks];
#pragma unroll
        for (int i = 0; i < 8; ++i) {
          float y = fmaxf(bf2f(tv[i]) * sc[ks][i] + sh[ks][i], 0.f);
          fa[ks][i] = (short)f2bf_bits(y);
        }
      }
    }

    // ---- matmul1: V = X*RW ; write V^T (bf16, swizzled) to LDS ----
#pragma unroll
    for (int rt = 0; rt < 4; ++rt) {
      fvec4 va = fvec4{0.f,0.f,0.f,0.f};
      va = __builtin_amdgcn_mfma_f32_16x16x32_bf16(fa[0], frw[rt][0], va, 0, 0, 0);
      va = __builtin_amdgcn_mfma_f32_16x16x32_bf16(fa[1], frw[rt][1], va, 0, 0, 0);
      int ridx = rt * 16 + m;
      int chunk = 2 * w + (g >> 1);
      int byte = ridx * 128 + ((chunk ^ (ridx & 7)) << 4) + ((g & 1) * 8);
      *(usvec4*)((char*)(&vt[cur][0]) + byte) = pack4(va);
    }

    // LDS-only barrier: drains ds ops, leaves global prefetch/stores in flight
    asm volatile("s_waitcnt lgkmcnt(0)\n\ts_barrier" ::: "memory");

    // ---- matmul2: Z^T = V^T * LW (o-tile = w) ----
    fvec4 za[4];
#pragma unroll
    for (int rt = 0; rt < 4; ++rt) za[rt] = fvec4{0.f,0.f,0.f,0.f};
#pragma unroll
    for (int ks = 0; ks < 2; ++ks) {
#pragma unroll
      for (int rt = 0; rt < 4; ++rt) {
        int ridx = rt * 16 + m;
        int byte = ridx * 128 + (((ks * 4 + g) ^ (ridx & 7)) << 4);
        bfrag8 av = *(const bfrag8*)((const char*)(&vt[cur][0]) + byte);
        za[rt] = __builtin_amdgcn_mfma_f32_16x16x32_bf16(av, flw[ks], za[rt], 0, 0, 0);
      }
    }

    // ---- epilogue ----
    if constexpr (LAYER == 1) {
#pragma unroll
      for (int rt = 0; rt < 4; ++rt) {
        fvec4 z = za[rt] + cb[rt];
        s1[rt] += z; q1[rt] += z * z;
        *(usvec4*)(t1 + (size_t)b * NFEAT +
                   (w * 16 + m) * 64 + rt * 16 + g * 4) = pack4(z);
      }
    } else {
      fvec4* pout = (fvec4*)(outf + (size_t)b * NFEAT);
#pragma unroll
      for (int rt = 0; rt < 4; ++rt) {
        int fi = ((w * 16 + m) * 64 + rt * 16 + g * 4) >> 2;
        pout[fi] = pfr[cur][rt] + za[rt] + cb[rt];
      }
    }
  }

  if constexpr (LAYER == 1) {
    // bn1 partials (bf16): each feature owned by exactly one thread -> plain writes
#pragma unroll
    for (int rt = 0; rt < 4; ++rt) {
      int vf = (w * 16 + m) * 64 + rt * 16 + g * 4;
      *(usvec4*)(p1 + (size_t)bid * 8192 + vf)        = pack4(s1[rt]);
      *(usvec4*)(p1 + (size_t)bid * 8192 + 4096 + vf) = pack4(q1[rt]);
    }
  }
}

extern "C" void kernel_launch(void* const* d_in, const int* in_sizes, int n_in,
                              void* d_out, int out_size, void* d_ws, size_t ws_size,
                              hipStream_t stream) {
  (void)in_sizes; (void)n_in; (void)out_size; (void)ws_size;
  const float* x    = (const float*)d_in[0];
  const float* g0   = (const float*)d_in[1];
  const float* b0   = (const float*)d_in[2];
  const float* g1   = (const float*)d_in[3];
  const float* b1   = (const float*)d_in[4];
  const float* k1lw = (const float*)d_in[5];
  const float* k1lb = (const float*)d_in[6];
  const float* k1rw = (const float*)d_in[7];
  const float* k1rb = (const float*)d_in[8];
  const float* k2lw = (const float*)d_in[9];
  const float* k2lb = (const float*)d_in[10];
  const float* k2rw = (const float*)d_in[11];
  const float* k2rb = (const float*)d_in[12];
  char* ws = (char*)d_ws;

  unsigned short* p0  = (unsigned short*)(ws + WS_P0);
  unsigned short* p1  = (unsigned short*)(ws + WS_P1);
  unsigned short* t1  = (unsigned short*)(ws + WS_T1);
  float* sc0 = (float*)(ws + WS_SC0);
  float* sh0 = (float*)(ws + WS_SH0);
  float* sc1 = (float*)(ws + WS_SC1);
  float* sh1 = (float*)(ws + WS_SH1);
  float* c1  = (float*)(ws + WS_C1);
  float* c2  = (float*)(ws + WS_C2);

  k_bn0part<<<1024, 256, 0, stream>>>(x, p0);
  k_prep0<<<96, 256, 0, stream>>>(p0, g0, b0, sc0, sh0,
                                  k1lb, k1rw, k1rb, k2lb, k2rw, k2rb, c1, c2);
  k_kron<1, 8><<<NROWS / 8, 256, 0, stream>>>(x, k1lw, k1rw, sc0, sh0, c1,
                                              t1, nullptr, p1);
  k_red1<<<64, 256, 0, stream>>>(p1, g1, b1, sc1, sh1);
  k_kron<2, 8><<<NROWS / 8, 256, 0, stream>>>(x, k2lw, k2rw, sc1, sh1, c2,
                                              t1, (float*)d_out, nullptr);
}

// Round 6
// 383.195 us; speedup vs baseline: 1.3251x; 1.0148x over previous
//
#include <hip/hip_runtime.h>

#define NROWS 16384
#define NFEAT 4096

typedef __attribute__((ext_vector_type(8))) short          bfrag8;  // 8 x bf16
typedef __attribute__((ext_vector_type(4))) float          fvec4;
typedef __attribute__((ext_vector_type(4))) unsigned short usvec4;
typedef __attribute__((ext_vector_type(8))) unsigned short usvec8;

// ---- d_ws layout (byte offsets; uses ~320 MiB of the 1 GiB ws) ----
#define WS_P0   ((size_t)0)            // bn0 partials: 1024 sets x 16 KB (bf16 sum|sumsq)
#define WS_P1   ((size_t)16 << 20)     // bn1 partials: 2048 sets x 16 KB
#define WS_SC0  ((size_t)48 << 20)     // f32[4096] scale0
#define WS_SH0  (WS_SC0 + 16384)       // f32[4096] shift0
#define WS_SC1  (WS_SC0 + 32768)       // f32[4096] scale1
#define WS_SH1  (WS_SC0 + 49152)       // f32[4096] shift1
#define WS_C1   (WS_SC0 + 65536)       // f32[4096] C1[o][r]
#define WS_C2   (WS_SC0 + 81920)       // f32[4096] C2[o][r]
#define WS_T1   ((size_t)64 << 20)     // t1: 16384 rows x 8 KB bf16
#define WS_XB   ((size_t)192 << 20)    // xb: bf16(x), 16384 rows x 8 KB

__device__ __forceinline__ unsigned short f2bf_bits(float f) {
  unsigned u = __builtin_bit_cast(unsigned, f);
  u += 0x7FFFu + ((u >> 16) & 1u);          // round-to-nearest-even
  return (unsigned short)(u >> 16);
}
__device__ __forceinline__ float bf2f(unsigned short b) {
  return __builtin_bit_cast(float, ((unsigned)b) << 16);
}
__device__ __forceinline__ usvec4 pack4(fvec4 a) {
  usvec4 p;
#pragma unroll
  for (int e = 0; e < 4; ++e) p[e] = f2bf_bits(a[e]);
  return p;
}
__device__ __forceinline__ fvec4 unpack4(usvec4 p) {
  return fvec4{bf2f(p[0]), bf2f(p[1]), bf2f(p[2]), bf2f(p[3])};
}

// ---------------- BN0 partial sums + x -> bf16 cast ----------------
__global__ __launch_bounds__(256) void k_bn0part(const float* __restrict__ x,
                                                 unsigned short* __restrict__ p0,
                                                 unsigned short* __restrict__ xb) {
  const int t = threadIdx.x, p = blockIdx.x;          // 1024 blocks, 16 rows each
  fvec4 s[4], sq[4];
#pragma unroll
  for (int q = 0; q < 4; ++q) { s[q] = fvec4{0.f,0.f,0.f,0.f}; sq[q] = s[q]; }
  for (int r = p * 16; r < p * 16 + 16; ++r) {
    const fvec4* row = (const fvec4*)(x + (size_t)r * NFEAT);
    usvec4* xrow = (usvec4*)(xb + (size_t)r * NFEAT);
#pragma unroll
    for (int q = 0; q < 4; ++q) {
      fvec4 v = row[t + 256 * q];
      s[q] += v; sq[q] += v * v;
      xrow[t + 256 * q] = pack4(v);
    }
  }
#pragma unroll
  for (int q = 0; q < 4; ++q) {
    int f0 = (t + 256 * q) * 4;
    *(usvec4*)(p0 + (size_t)p * 8192 + f0)        = pack4(s[q]);
    *(usvec4*)(p0 + (size_t)p * 8192 + 4096 + f0) = pack4(sq[q]);
  }
}

// ---------------- shared reduce body: bf16 partials -> f32 scale|shift ----------------
__device__ __forceinline__ void red_body(fvec4 (*red)[16][2],
                                         const unsigned short* __restrict__ parts,
                                         int nsets,
                                         const float* __restrict__ g,
                                         const float* __restrict__ bta,
                                         float* __restrict__ sc_out,
                                         float* __restrict__ sh_out, int j) {
  const int t = threadIdx.x;
  const int fc = t & 15, c = t >> 4;
  const int v = j * 64 + fc * 4;
  fvec4 s = fvec4{0.f,0.f,0.f,0.f}, q = s;
  for (int i = c; i < nsets; i += 16) {
    s += unpack4(*(const usvec4*)(parts + (size_t)i * 8192 + v));
    q += unpack4(*(const usvec4*)(parts + (size_t)i * 8192 + 4096 + v));
  }
  red[c][fc][0] = s; red[c][fc][1] = q;
  __syncthreads();
  if (c == 0) {
    fvec4 S = red[0][fc][0], Q = red[0][fc][1];
#pragma unroll
    for (int k = 1; k < 16; ++k) { S += red[k][fc][0]; Q += red[k][fc][1]; }
    fvec4 SC, SH;
    const float inv = 1.0f / NROWS;
#pragma unroll
    for (int e = 0; e < 4; ++e) {
      float mean = S[e] * inv;
      float var  = Q[e] * inv - mean * mean;
      float scv  = g[v + e] * rsqrtf(var + 1e-3f);
      SC[e] = scv; SH[e] = bta[v + e] - mean * scv;
    }
    *(fvec4*)(sc_out + v) = SC;
    *(fvec4*)(sh_out + v) = SH;
  }
}

// ---------------- prep0: red0 (blocks 0-63) + C1/C2 (blocks 64-95) ----------------
__global__ __launch_bounds__(256) void k_prep0(const unsigned short* __restrict__ p0,
                                               const float* __restrict__ g0,
                                               const float* __restrict__ b0,
                                               float* __restrict__ sc0,
                                               float* __restrict__ sh0,
                                               const float* __restrict__ lb1,
                                               const float* __restrict__ rw1,
                                               const float* __restrict__ rb1,
                                               const float* __restrict__ lb2,
                                               const float* __restrict__ rw2,
                                               const float* __restrict__ rb2,
                                               float* __restrict__ c1,
                                               float* __restrict__ c2) {
  __shared__ fvec4 red[16][16][2];
  if (blockIdx.x < 64) {
    red_body(red, p0, 1024, g0, b0, sc0, sh0, blockIdx.x);
  } else {
    const int bb   = blockIdx.x - 64;
    const int idx  = (bb & 15) * 256 + threadIdx.x;   // 0..4095
    const int part = bb >> 4;                          // 0 -> C1, 1 -> C2
    const float* lb = part ? lb2 : lb1;
    const float* rw = part ? rw2 : rw1;
    const float* rb = part ? rb2 : rb1;
    int r = idx >> 6, o = idx & 63;
    float acc = rb[o * 64 + r];
    for (int j = 0; j < 64; ++j) acc += lb[o * 64 + j] * rw[j * 64 + r];
    (part ? c2 : c1)[o * 64 + r] = acc;                // C[o][r]
  }
}

// ---------------- red1: bn1 partials -> scale1|shift1 ----------------
__global__ __launch_bounds__(256) void k_red1(const unsigned short* __restrict__ p1,
                                              const float* __restrict__ g1,
                                              const float* __restrict__ b1,
                                              float* __restrict__ sc1,
                                              float* __restrict__ sh1) {
  __shared__ fvec4 red[16][16][2];
  red_body(red, p1, 2048, g1, b1, sc1, sh1, blockIdx.x);
}

// ---------------- kron block (both layers), depth-2 software pipeline ----------------
// Per row b: X[k][j] = in[b][64k+j] (post BN+relu, bf16).
//   V  = X * RW      (M=k, N=r, K=j)   wave w owns k-tile w
//   Z^T= V^T * LW    (M=r, N=o, K=k)   wave w owns o-tile w
// LAYER==1: A-src = xb(bf16)+BN0; out: t1 bf16 + bn1 bf16 partial set bid.
// LAYER==2: A-src = t1(bf16)+BN1; out: float xb + Z + C2 to d_out.
template <int LAYER, int RPBN>
__global__ __launch_bounds__(256) void k_kron(const unsigned short* __restrict__ xb,
                                              const float* __restrict__ lw,
                                              const float* __restrict__ rw,
                                              const float* __restrict__ scv,
                                              const float* __restrict__ shv,
                                              const float* __restrict__ cn,
                                              unsigned short* __restrict__ t1,
                                              float* __restrict__ outf,
                                              unsigned short* __restrict__ p1) {
  __shared__ unsigned short vt[2][64 * 64];   // V^T bf16, XOR-swizzled, double-buffered
  const int tid = threadIdx.x, bid = blockIdx.x;
  const int w = tid >> 6, l = tid & 63, m = l & 15, g = l >> 4;
  const int r0 = bid * RPBN;
  const unsigned short* asrc = (LAYER == 1) ? xb : t1;

  // RW B-frags: frw[rt][ks][i] = RW[ks*32+g*8+i][rt*16+m]
  bfrag8 frw[4][2];
#pragma unroll
  for (int rt = 0; rt < 4; ++rt)
#pragma unroll
    for (int ks = 0; ks < 2; ++ks)
#pragma unroll
      for (int i = 0; i < 8; ++i)
        frw[rt][ks][i] = (short)f2bf_bits(rw[(ks * 32 + g * 8 + i) * 64 + rt * 16 + m]);

  // LW B-frags (o-tile w): flw[ks][i] = LW[ks*32+g*8+i][w*16+m]
  bfrag8 flw[2];
#pragma unroll
  for (int ks = 0; ks < 2; ++ks)
#pragma unroll
    for (int i = 0; i < 8; ++i)
      flw[ks][i] = (short)f2bf_bits(lw[(ks * 32 + g * 8 + i) * 64 + w * 16 + m]);

  // bias: cb[rt] = C[o=w*16+m][r=rt*16+g*4 .. +3]
  fvec4 cb[4];
#pragma unroll
  for (int rt = 0; rt < 4; ++rt)
    cb[rt] = *(const fvec4*)(cn + (w * 16 + m) * 64 + rt * 16 + g * 4);

  // BN scale/shift for this lane's A-frag features (f32, L2-broadcast)
  float sc[2][8], sh[2][8];
#pragma unroll
  for (int ks = 0; ks < 2; ++ks) {
    int f = (w * 16 + m) * 64 + ks * 32 + g * 8;
    fvec4 a0 = *(const fvec4*)(scv + f), a1 = *(const fvec4*)(scv + f + 4);
    fvec4 h0 = *(const fvec4*)(shv + f), h1 = *(const fvec4*)(shv + f + 4);
#pragma unroll
    for (int e = 0; e < 4; ++e) {
      sc[ks][e] = a0[e]; sc[ks][4 + e] = a1[e];
      sh[ks][e] = h0[e]; sh[ks][4 + e] = h1[e];
    }
  }

  fvec4 s1[4], q1[4];
#pragma unroll
  for (int rt = 0; rt < 4; ++rt) { s1[rt] = fvec4{0.f,0.f,0.f,0.f}; q1[rt] = s1[rt]; }

  // depth-2 prefetch buffers (2 slots; consume-then-reissue -> 2 rows in flight)
  usvec8 pfa[2][2];   // A-source (bf16): 2 x 16B per row
  usvec4 pfr[2][4];   // layer2 residual (bf16): 4 x 8B per row

  {
    const usvec8* pt0 = (const usvec8*)(asrc + (size_t)r0 * NFEAT);
    const usvec8* pt1 = (const usvec8*)(asrc + (size_t)(r0 + 1) * NFEAT);
    pfa[0][0] = pt0[(w * 16 + m) * 8 + g];
    pfa[0][1] = pt0[(w * 16 + m) * 8 + 4 + g];
    pfa[1][0] = pt1[(w * 16 + m) * 8 + g];
    pfa[1][1] = pt1[(w * 16 + m) * 8 + 4 + g];
    if constexpr (LAYER == 2) {
#pragma unroll
      for (int rt = 0; rt < 4; ++rt) {
        int off = (w * 16 + m) * 64 + rt * 16 + g * 4;
        pfr[0][rt] = *(const usvec4*)(xb + (size_t)r0 * NFEAT + off);
        pfr[1][rt] = *(const usvec4*)(xb + (size_t)(r0 + 1) * NFEAT + off);
      }
    }
  }

#pragma unroll
  for (int rr = 0; rr < RPBN; ++rr) {
    const int b = r0 + rr;
    const int cur = rr & 1;

    // ---- consume A (loads issued 2 iterations ago): BN + relu + pack ----
    bfrag8 fa[2];
#pragma unroll
    for (int ks = 0; ks < 2; ++ks) {
      usvec8 tv = pfa[cur][ks];
#pragma unroll
      for (int i = 0; i < 8; ++i) {
        float y = fmaxf(bf2f(tv[i]) * sc[ks][i] + sh[ks][i], 0.f);
        fa[ks][i] = (short)f2bf_bits(y);
      }
    }

    // ---- reissue A-slot for row rr+2 (2 rows in flight) ----
    if (rr + 2 < RPBN) {
      const usvec8* pt = (const usvec8*)(asrc + (size_t)(b + 2) * NFEAT);
      pfa[cur][0] = pt[(w * 16 + m) * 8 + g];
      pfa[cur][1] = pt[(w * 16 + m) * 8 + 4 + g];
    }

    // ---- matmul1: V = X*RW ; write V^T (bf16, swizzled) to LDS ----
#pragma unroll
    for (int rt = 0; rt < 4; ++rt) {
      fvec4 va = fvec4{0.f,0.f,0.f,0.f};
      va = __builtin_amdgcn_mfma_f32_16x16x32_bf16(fa[0], frw[rt][0], va, 0, 0, 0);
      va = __builtin_amdgcn_mfma_f32_16x16x32_bf16(fa[1], frw[rt][1], va, 0, 0, 0);
      int ridx = rt * 16 + m;
      int chunk = 2 * w + (g >> 1);
      int byte = ridx * 128 + ((chunk ^ (ridx & 7)) << 4) + ((g & 1) * 8);
      *(usvec4*)((char*)(&vt[cur][0]) + byte) = pack4(va);
    }

    // LDS-only barrier: drains ds ops, leaves global prefetch/stores in flight
    asm volatile("s_waitcnt lgkmcnt(0)\n\ts_barrier" ::: "memory");

    // ---- matmul2: Z^T = V^T * LW (o-tile = w) ----
    fvec4 za[4];
#pragma unroll
    for (int rt = 0; rt < 4; ++rt) za[rt] = fvec4{0.f,0.f,0.f,0.f};
#pragma unroll
    for (int ks = 0; ks < 2; ++ks) {
#pragma unroll
      for (int rt = 0; rt < 4; ++rt) {
        int ridx = rt * 16 + m;
        int byte = ridx * 128 + (((ks * 4 + g) ^ (ridx & 7)) << 4);
        bfrag8 av = *(const bfrag8*)((const char*)(&vt[cur][0]) + byte);
        za[rt] = __builtin_amdgcn_mfma_f32_16x16x32_bf16(av, flw[ks], za[rt], 0, 0, 0);
      }
    }

    // ---- epilogue ----
    if constexpr (LAYER == 1) {
#pragma unroll
      for (int rt = 0; rt < 4; ++rt) {
        fvec4 z = za[rt] + cb[rt];
        s1[rt] += z; q1[rt] += z * z;
        *(usvec4*)(t1 + (size_t)b * NFEAT +
                   (w * 16 + m) * 64 + rt * 16 + g * 4) = pack4(z);
      }
    } else {
      fvec4* pout = (fvec4*)(outf + (size_t)b * NFEAT);
#pragma unroll
      for (int rt = 0; rt < 4; ++rt) {
        int fi = ((w * 16 + m) * 64 + rt * 16 + g * 4) >> 2;
        pout[fi] = unpack4(pfr[cur][rt]) + za[rt] + cb[rt];
      }
      // reissue residual slot for row rr+2
      if (rr + 2 < RPBN) {
#pragma unroll
        for (int rt = 0; rt < 4; ++rt) {
          int off = (w * 16 + m) * 64 + rt * 16 + g * 4;
          pfr[cur][rt] = *(const usvec4*)(xb + (size_t)(b + 2) * NFEAT + off);
        }
      }
    }
  }

  if constexpr (LAYER == 1) {
    // bn1 partials (bf16): each feature owned by exactly one thread -> plain writes
#pragma unroll
    for (int rt = 0; rt < 4; ++rt) {
      int vf = (w * 16 + m) * 64 + rt * 16 + g * 4;
      *(usvec4*)(p1 + (size_t)bid * 8192 + vf)        = pack4(s1[rt]);
      *(usvec4*)(p1 + (size_t)bid * 8192 + 4096 + vf) = pack4(q1[rt]);
    }
  }
}

extern "C" void kernel_launch(void* const* d_in, const int* in_sizes, int n_in,
                              void* d_out, int out_size, void* d_ws, size_t ws_size,
                              hipStream_t stream) {
  (void)in_sizes; (void)n_in; (void)out_size; (void)ws_size;
  const float* x    = (const float*)d_in[0];
  const float* g0   = (const float*)d_in[1];
  const float* b0   = (const float*)d_in[2];
  const float* g1   = (const float*)d_in[3];
  const float* b1   = (const float*)d_in[4];
  const float* k1lw = (const float*)d_in[5];
  const float* k1lb = (const float*)d_in[6];
  const float* k1rw = (const float*)d_in[7];
  const float* k1rb = (const float*)d_in[8];
  const float* k2lw = (const float*)d_in[9];
  const float* k2lb = (const float*)d_in[10];
  const float* k2rw = (const float*)d_in[11];
  const float* k2rb = (const float*)d_in[12];
  char* ws = (char*)d_ws;

  unsigned short* p0  = (unsigned short*)(ws + WS_P0);
  unsigned short* p1  = (unsigned short*)(ws + WS_P1);
  unsigned short* t1  = (unsigned short*)(ws + WS_T1);
  unsigned short* xb  = (unsigned short*)(ws + WS_XB);
  float* sc0 = (float*)(ws + WS_SC0);
  float* sh0 = (float*)(ws + WS_SH0);
  float* sc1 = (float*)(ws + WS_SC1);
  float* sh1 = (float*)(ws + WS_SH1);
  float* c1  = (float*)(ws + WS_C1);
  float* c2  = (float*)(ws + WS_C2);

  k_bn0part<<<1024, 256, 0, stream>>>(x, p0, xb);
  k_prep0<<<96, 256, 0, stream>>>(p0, g0, b0, sc0, sh0,
                                  k1lb, k1rw, k1rb, k2lb, k2rw, k2rb, c1, c2);
  k_kron<1, 8><<<NROWS / 8, 256, 0, stream>>>(xb, k1lw, k1rw, sc0, sh0, c1,
                                              t1, nullptr, p1);
  k_red1<<<64, 256, 0, stream>>>(p1, g1, b1, sc1, sh1);
  k_kron<2, 8><<<NROWS / 8, 256, 0, stream>>>(xb, k2lw, k2rw, sc1, sh1, c2,
                                              t1, (float*)d_out, nullptr);
}

// Round 7
// 348.823 us; speedup vs baseline: 1.4557x; 1.0985x over previous
//
#include <hip/hip_runtime.h>

#define NROWS 16384
#define NFEAT 4096

typedef __attribute__((ext_vector_type(8))) short          bfrag8;  // 8 x bf16
typedef __attribute__((ext_vector_type(4))) float          fvec4;
typedef __attribute__((ext_vector_type(2))) float          fvec2;
typedef __attribute__((ext_vector_type(4))) unsigned short usvec4;
typedef __attribute__((ext_vector_type(8))) unsigned short usvec8;
typedef __attribute__((ext_vector_type(2))) unsigned int   uvec2;

// ---- d_ws layout (byte offsets; uses ~320 MiB of the 1 GiB ws) ----
#define WS_P0   ((size_t)0)            // bn0 partials: 1024 sets x 16 KB (bf16 sum|sumsq)
#define WS_P1   ((size_t)16 << 20)     // bn1 partials: 2048 sets x 16 KB
#define WS_SC0  ((size_t)48 << 20)     // f32[4096] scale0
#define WS_SH0  (WS_SC0 + 16384)       // f32[4096] shift0
#define WS_SC1  (WS_SC0 + 32768)       // f32[4096] scale1
#define WS_SH1  (WS_SC0 + 49152)       // f32[4096] shift1
#define WS_C1   (WS_SC0 + 65536)       // f32[4096] C1[o][r]
#define WS_C2   (WS_SC0 + 81920)       // f32[4096] C2[o][r]
#define WS_T1   ((size_t)64 << 20)     // t1: 16384 rows x 4 KB fp8 e4m3
#define WS_XB   ((size_t)192 << 20)    // xb: bf16(x), 16384 rows x 8 KB

__device__ __forceinline__ unsigned short f2bf_bits(float f) {
  unsigned u = __builtin_bit_cast(unsigned, f);
  u += 0x7FFFu + ((u >> 16) & 1u);          // round-to-nearest-even
  return (unsigned short)(u >> 16);
}
__device__ __forceinline__ float bf2f(unsigned short b) {
  return __builtin_bit_cast(float, ((unsigned)b) << 16);
}
__device__ __forceinline__ usvec4 pack4(fvec4 a) {
  usvec4 p;
#pragma unroll
  for (int e = 0; e < 4; ++e) p[e] = f2bf_bits(a[e]);
  return p;
}
__device__ __forceinline__ fvec4 unpack4(usvec4 p) {
  return fvec4{bf2f(p[0]), bf2f(p[1]), bf2f(p[2]), bf2f(p[3])};
}

// ---------------- BN0 partial sums + x -> bf16 cast ----------------
__global__ __launch_bounds__(256) void k_bn0part(const float* __restrict__ x,
                                                 unsigned short* __restrict__ p0,
                                                 unsigned short* __restrict__ xb) {
  const int t = threadIdx.x, p = blockIdx.x;          // 1024 blocks, 16 rows each
  fvec4 s[4], sq[4];
#pragma unroll
  for (int q = 0; q < 4; ++q) { s[q] = fvec4{0.f,0.f,0.f,0.f}; sq[q] = s[q]; }
  for (int r = p * 16; r < p * 16 + 16; ++r) {
    const fvec4* row = (const fvec4*)(x + (size_t)r * NFEAT);
    usvec4* xrow = (usvec4*)(xb + (size_t)r * NFEAT);
#pragma unroll
    for (int q = 0; q < 4; ++q) {
      fvec4 v = row[t + 256 * q];
      s[q] += v; sq[q] += v * v;
      xrow[t + 256 * q] = pack4(v);
    }
  }
#pragma unroll
  for (int q = 0; q < 4; ++q) {
    int f0 = (t + 256 * q) * 4;
    *(usvec4*)(p0 + (size_t)p * 8192 + f0)        = pack4(s[q]);
    *(usvec4*)(p0 + (size_t)p * 8192 + 4096 + f0) = pack4(sq[q]);
  }
}

// ---------------- shared reduce body: bf16 partials -> f32 scale|shift ----------------
__device__ __forceinline__ void red_body(fvec4 (*red)[16][2],
                                         const unsigned short* __restrict__ parts,
                                         int nsets,
                                         const float* __restrict__ g,
                                         const float* __restrict__ bta,
                                         float* __restrict__ sc_out,
                                         float* __restrict__ sh_out, int j) {
  const int t = threadIdx.x;
  const int fc = t & 15, c = t >> 4;
  const int v = j * 64 + fc * 4;
  fvec4 s = fvec4{0.f,0.f,0.f,0.f}, q = s;
  for (int i = c; i < nsets; i += 16) {
    s += unpack4(*(const usvec4*)(parts + (size_t)i * 8192 + v));
    q += unpack4(*(const usvec4*)(parts + (size_t)i * 8192 + 4096 + v));
  }
  red[c][fc][0] = s; red[c][fc][1] = q;
  __syncthreads();
  if (c == 0) {
    fvec4 S = red[0][fc][0], Q = red[0][fc][1];
#pragma unroll
    for (int k = 1; k < 16; ++k) { S += red[k][fc][0]; Q += red[k][fc][1]; }
    fvec4 SC, SH;
    const float inv = 1.0f / NROWS;
#pragma unroll
    for (int e = 0; e < 4; ++e) {
      float mean = S[e] * inv;
      float var  = Q[e] * inv - mean * mean;
      float scv  = g[v + e] * rsqrtf(var + 1e-3f);
      SC[e] = scv; SH[e] = bta[v + e] - mean * scv;
    }
    *(fvec4*)(sc_out + v) = SC;
    *(fvec4*)(sh_out + v) = SH;
  }
}

// ---------------- prep0: red0 (blocks 0-63) + C1/C2 (blocks 64-95) ----------------
__global__ __launch_bounds__(256) void k_prep0(const unsigned short* __restrict__ p0,
                                               const float* __restrict__ g0,
                                               const float* __restrict__ b0,
                                               float* __restrict__ sc0,
                                               float* __restrict__ sh0,
                                               const float* __restrict__ lb1,
                                               const float* __restrict__ rw1,
                                               const float* __restrict__ rb1,
                                               const float* __restrict__ lb2,
                                               const float* __restrict__ rw2,
                                               const float* __restrict__ rb2,
                                               float* __restrict__ c1,
                                               float* __restrict__ c2) {
  __shared__ fvec4 red[16][16][2];
  if (blockIdx.x < 64) {
    red_body(red, p0, 1024, g0, b0, sc0, sh0, blockIdx.x);
  } else {
    const int bb   = blockIdx.x - 64;
    const int idx  = (bb & 15) * 256 + threadIdx.x;   // 0..4095
    const int part = bb >> 4;                          // 0 -> C1, 1 -> C2
    const float* lb = part ? lb2 : lb1;
    const float* rw = part ? rw2 : rw1;
    const float* rb = part ? rb2 : rb1;
    int r = idx >> 6, o = idx & 63;
    float acc = rb[o * 64 + r];
    for (int j = 0; j < 64; ++j) acc += lb[o * 64 + j] * rw[j * 64 + r];
    (part ? c2 : c1)[o * 64 + r] = acc;                // C[o][r]
  }
}

// ---------------- red1: bn1 partials -> scale1|shift1 ----------------
__global__ __launch_bounds__(256) void k_red1(const unsigned short* __restrict__ p1,
                                              const float* __restrict__ g1,
                                              const float* __restrict__ b1,
                                              float* __restrict__ sc1,
                                              float* __restrict__ sh1) {
  __shared__ fvec4 red[16][16][2];
  red_body(red, p1, 2048, g1, b1, sc1, sh1, blockIdx.x);
}

// ---------------- kron block (both layers), depth-2 software pipeline ----------------
// Per row b: X[k][j] = in[b][64k+j] (post BN+relu, bf16).
//   V  = X * RW      (M=k, N=r, K=j)   wave w owns k-tile w
//   Z^T= V^T * LW    (M=r, N=o, K=k)   wave w owns o-tile w
// LAYER==1: A-src = xb(bf16)+BN0; out: t1 fp8 + bn1 bf16 partial set bid.
// LAYER==2: A-src = t1(fp8)+BN1; out: float xb + Z + C2 to d_out.
template <int LAYER, int RPBN>
__global__ __launch_bounds__(256) void k_kron(const unsigned short* __restrict__ xb,
                                              const float* __restrict__ lw,
                                              const float* __restrict__ rw,
                                              const float* __restrict__ scv,
                                              const float* __restrict__ shv,
                                              const float* __restrict__ cn,
                                              unsigned char* __restrict__ t1q,
                                              float* __restrict__ outf,
                                              unsigned short* __restrict__ p1) {
  __shared__ unsigned short vt[2][64 * 64];   // V^T bf16, XOR-swizzled, double-buffered
  const int tid = threadIdx.x, bid = blockIdx.x;
  const int w = tid >> 6, l = tid & 63, m = l & 15, g = l >> 4;
  const int r0 = bid * RPBN;

  // RW B-frags: frw[rt][ks][i] = RW[ks*32+g*8+i][rt*16+m]
  bfrag8 frw[4][2];
#pragma unroll
  for (int rt = 0; rt < 4; ++rt)
#pragma unroll
    for (int ks = 0; ks < 2; ++ks)
#pragma unroll
      for (int i = 0; i < 8; ++i)
        frw[rt][ks][i] = (short)f2bf_bits(rw[(ks * 32 + g * 8 + i) * 64 + rt * 16 + m]);

  // LW B-frags (o-tile w): flw[ks][i] = LW[ks*32+g*8+i][w*16+m]
  bfrag8 flw[2];
#pragma unroll
  for (int ks = 0; ks < 2; ++ks)
#pragma unroll
    for (int i = 0; i < 8; ++i)
      flw[ks][i] = (short)f2bf_bits(lw[(ks * 32 + g * 8 + i) * 64 + w * 16 + m]);

  // bias: cb[rt] = C[o=w*16+m][r=rt*16+g*4 .. +3]
  fvec4 cb[4];
#pragma unroll
  for (int rt = 0; rt < 4; ++rt)
    cb[rt] = *(const fvec4*)(cn + (w * 16 + m) * 64 + rt * 16 + g * 4);

  // BN scale/shift for this lane's A-frag features (f32, L2-broadcast)
  float sc[2][8], sh[2][8];
#pragma unroll
  for (int ks = 0; ks < 2; ++ks) {
    int f = (w * 16 + m) * 64 + ks * 32 + g * 8;
    fvec4 a0 = *(const fvec4*)(scv + f), a1 = *(const fvec4*)(scv + f + 4);
    fvec4 h0 = *(const fvec4*)(shv + f), h1 = *(const fvec4*)(shv + f + 4);
#pragma unroll
    for (int e = 0; e < 4; ++e) {
      sc[ks][e] = a0[e]; sc[ks][4 + e] = a1[e];
      sh[ks][e] = h0[e]; sh[ks][4 + e] = h1[e];
    }
  }

  fvec4 s1[4], q1[4];
#pragma unroll
  for (int rt = 0; rt < 4; ++rt) { s1[rt] = fvec4{0.f,0.f,0.f,0.f}; q1[rt] = s1[rt]; }

  // depth-2 prefetch buffers (2 slots; consume-then-reissue -> 2 rows in flight)
  usvec8 pfa[2][2];   // layer1 A-source (bf16): 2 x 16B per row
  uvec2  pfq[2][2];   // layer2 A-source (fp8): 2 x 8B per row
  usvec4 pfr[2][4];   // layer2 residual (bf16): 4 x 8B per row

  if constexpr (LAYER == 1) {
    const usvec8* pt0 = (const usvec8*)(xb + (size_t)r0 * NFEAT);
    const usvec8* pt1 = (const usvec8*)(xb + (size_t)(r0 + 1) * NFEAT);
    pfa[0][0] = pt0[(w * 16 + m) * 8 + g];
    pfa[0][1] = pt0[(w * 16 + m) * 8 + 4 + g];
    pfa[1][0] = pt1[(w * 16 + m) * 8 + g];
    pfa[1][1] = pt1[(w * 16 + m) * 8 + 4 + g];
  } else {
    const uvec2* pq0 = (const uvec2*)(t1q + (size_t)r0 * NFEAT);
    const uvec2* pq1 = (const uvec2*)(t1q + (size_t)(r0 + 1) * NFEAT);
    pfq[0][0] = pq0[(w * 16 + m) * 8 + g];
    pfq[0][1] = pq0[(w * 16 + m) * 8 + 4 + g];
    pfq[1][0] = pq1[(w * 16 + m) * 8 + g];
    pfq[1][1] = pq1[(w * 16 + m) * 8 + 4 + g];
#pragma unroll
    for (int rt = 0; rt < 4; ++rt) {
      int off = (w * 16 + m) * 64 + rt * 16 + g * 4;
      pfr[0][rt] = *(const usvec4*)(xb + (size_t)r0 * NFEAT + off);
      pfr[1][rt] = *(const usvec4*)(xb + (size_t)(r0 + 1) * NFEAT + off);
    }
  }

#pragma unroll
  for (int rr = 0; rr < RPBN; ++rr) {
    const int b = r0 + rr;
    const int cur = rr & 1;

    // ---- consume A (loads issued 2 iterations ago): BN + relu + pack ----
    bfrag8 fa[2];
    if constexpr (LAYER == 1) {
#pragma unroll
      for (int ks = 0; ks < 2; ++ks) {
        usvec8 tv = pfa[cur][ks];
#pragma unroll
        for (int i = 0; i < 8; ++i) {
          float y = fmaxf(bf2f(tv[i]) * sc[ks][i] + sh[ks][i], 0.f);
          fa[ks][i] = (short)f2bf_bits(y);
        }
      }
    } else {
#pragma unroll
      for (int ks = 0; ks < 2; ++ks) {
        uvec2 tv = pfq[cur][ks];
        fvec2 d0 = __builtin_amdgcn_cvt_pk_f32_fp8((int)tv[0], false);
        fvec2 d1 = __builtin_amdgcn_cvt_pk_f32_fp8((int)tv[0], true);
        fvec2 d2 = __builtin_amdgcn_cvt_pk_f32_fp8((int)tv[1], false);
        fvec2 d3 = __builtin_amdgcn_cvt_pk_f32_fp8((int)tv[1], true);
        float xv[8] = {d0[0], d0[1], d1[0], d1[1], d2[0], d2[1], d3[0], d3[1]};
#pragma unroll
        for (int i = 0; i < 8; ++i) {
          float y = fmaxf(xv[i] * sc[ks][i] + sh[ks][i], 0.f);
          fa[ks][i] = (short)f2bf_bits(y);
        }
      }
    }

    // ---- reissue A-slot for row rr+2 (2 rows in flight) ----
    if (rr + 2 < RPBN) {
      if constexpr (LAYER == 1) {
        const usvec8* pt = (const usvec8*)(xb + (size_t)(b + 2) * NFEAT);
        pfa[cur][0] = pt[(w * 16 + m) * 8 + g];
        pfa[cur][1] = pt[(w * 16 + m) * 8 + 4 + g];
      } else {
        const uvec2* pq = (const uvec2*)(t1q + (size_t)(b + 2) * NFEAT);
        pfq[cur][0] = pq[(w * 16 + m) * 8 + g];
        pfq[cur][1] = pq[(w * 16 + m) * 8 + 4 + g];
      }
    }

    // ---- matmul1: V = X*RW ; write V^T (bf16, swizzled) to LDS ----
#pragma unroll
    for (int rt = 0; rt < 4; ++rt) {
      fvec4 va = fvec4{0.f,0.f,0.f,0.f};
      va = __builtin_amdgcn_mfma_f32_16x16x32_bf16(fa[0], frw[rt][0], va, 0, 0, 0);
      va = __builtin_amdgcn_mfma_f32_16x16x32_bf16(fa[1], frw[rt][1], va, 0, 0, 0);
      int ridx = rt * 16 + m;
      int chunk = 2 * w + (g >> 1);
      int byte = ridx * 128 + ((chunk ^ (ridx & 7)) << 4) + ((g & 1) * 8);
      *(usvec4*)((char*)(&vt[cur][0]) + byte) = pack4(va);
    }

    // LDS-only barrier: drain ds writes (lgkm) but leave global loads/stores
    // in flight across the barrier (no "memory" clobber -> no vmcnt drain).
    __builtin_amdgcn_sched_barrier(0);
    asm volatile("s_waitcnt lgkmcnt(0)");
    __builtin_amdgcn_s_barrier();
    __builtin_amdgcn_sched_barrier(0);

    // ---- matmul2: Z^T = V^T * LW (o-tile = w) ----
    fvec4 za[4];
#pragma unroll
    for (int rt = 0; rt < 4; ++rt) za[rt] = fvec4{0.f,0.f,0.f,0.f};
#pragma unroll
    for (int ks = 0; ks < 2; ++ks) {
#pragma unroll
      for (int rt = 0; rt < 4; ++rt) {
        int ridx = rt * 16 + m;
        int byte = ridx * 128 + (((ks * 4 + g) ^ (ridx & 7)) << 4);
        bfrag8 av = *(const bfrag8*)((const char*)(&vt[cur][0]) + byte);
        za[rt] = __builtin_amdgcn_mfma_f32_16x16x32_bf16(av, flw[ks], za[rt], 0, 0, 0);
      }
    }

    // ---- epilogue ----
    if constexpr (LAYER == 1) {
#pragma unroll
      for (int rt = 0; rt < 4; ++rt) {
        fvec4 z = za[rt] + cb[rt];
        s1[rt] += z; q1[rt] += z * z;
        int pq = __builtin_amdgcn_cvt_pk_fp8_f32(z[0], z[1], 0, false);
        pq     = __builtin_amdgcn_cvt_pk_fp8_f32(z[2], z[3], pq, true);
        *(unsigned*)(t1q + (size_t)b * NFEAT +
                     (w * 16 + m) * 64 + rt * 16 + g * 4) = (unsigned)pq;
      }
    } else {
      fvec4* pout = (fvec4*)(outf + (size_t)b * NFEAT);
#pragma unroll
      for (int rt = 0; rt < 4; ++rt) {
        int fi = ((w * 16 + m) * 64 + rt * 16 + g * 4) >> 2;
        pout[fi] = unpack4(pfr[cur][rt]) + za[rt] + cb[rt];
      }
      // reissue residual slot for row rr+2
      if (rr + 2 < RPBN) {
#pragma unroll
        for (int rt = 0; rt < 4; ++rt) {
          int off = (w * 16 + m) * 64 + rt * 16 + g * 4;
          pfr[cur][rt] = *(const usvec4*)(xb + (size_t)(b + 2) * NFEAT + off);
        }
      }
    }
  }

  if constexpr (LAYER == 1) {
    // bn1 partials (bf16): each feature owned by exactly one thread -> plain writes
#pragma unroll
    for (int rt = 0; rt < 4; ++rt) {
      int vf = (w * 16 + m) * 64 + rt * 16 + g * 4;
      *(usvec4*)(p1 + (size_t)bid * 8192 + vf)        = pack4(s1[rt]);
      *(usvec4*)(p1 + (size_t)bid * 8192 + 4096 + vf) = pack4(q1[rt]);
    }
  }
}

extern "C" void kernel_launch(void* const* d_in, const int* in_sizes, int n_in,
                              void* d_out, int out_size, void* d_ws, size_t ws_size,
                              hipStream_t stream) {
  (void)in_sizes; (void)n_in; (void)out_size; (void)ws_size;
  const float* x    = (const float*)d_in[0];
  const float* g0   = (const float*)d_in[1];
  const float* b0   = (const float*)d_in[2];
  const float* g1   = (const float*)d_in[3];
  const float* b1   = (const float*)d_in[4];
  const float* k1lw = (const float*)d_in[5];
  const float* k1lb = (const float*)d_in[6];
  const float* k1rw = (const float*)d_in[7];
  const float* k1rb = (const float*)d_in[8];
  const float* k2lw = (const float*)d_in[9];
  const float* k2lb = (const float*)d_in[10];
  const float* k2rw = (const float*)d_in[11];
  const float* k2rb = (const float*)d_in[12];
  char* ws = (char*)d_ws;

  unsigned short* p0  = (unsigned short*)(ws + WS_P0);
  unsigned short* p1  = (unsigned short*)(ws + WS_P1);
  unsigned char*  t1q = (unsigned char*)(ws + WS_T1);
  unsigned short* xb  = (unsigned short*)(ws + WS_XB);
  float* sc0 = (float*)(ws + WS_SC0);
  float* sh0 = (float*)(ws + WS_SH0);
  float* sc1 = (float*)(ws + WS_SC1);
  float* sh1 = (float*)(ws + WS_SH1);
  float* c1  = (float*)(ws + WS_C1);
  float* c2  = (float*)(ws + WS_C2);

  k_bn0part<<<1024, 256, 0, stream>>>(x, p0, xb);
  k_prep0<<<96, 256, 0, stream>>>(p0, g0, b0, sc0, sh0,
                                  k1lb, k1rw, k1rb, k2lb, k2rw, k2rb, c1, c2);
  k_kron<1, 8><<<NROWS / 8, 256, 0, stream>>>(xb, k1lw, k1rw, sc0, sh0, c1,
                                              t1q, nullptr, p1);
  k_red1<<<64, 256, 0, stream>>>(p1, g1, b1, sc1, sh1);
  k_kron<2, 8><<<NROWS / 8, 256, 0, stream>>>(xb, k2lw, k2rw, sc1, sh1, c2,
                                              t1q, (float*)d_out, nullptr);
}

// Round 9
// 326.097 us; speedup vs baseline: 1.5571x; 1.0697x over previous
//
#include <hip/hip_runtime.h>

#define NROWS 16384
#define NFEAT 4096

typedef __attribute__((ext_vector_type(8))) short          bfrag8;  // 8 x bf16
typedef __attribute__((ext_vector_type(4))) float          fvec4;
typedef __attribute__((ext_vector_type(2))) float          fvec2;
typedef __attribute__((ext_vector_type(4))) unsigned short usvec4;
typedef __attribute__((ext_vector_type(8))) unsigned short usvec8;
typedef __attribute__((ext_vector_type(2))) unsigned int   uvec2;
typedef __attribute__((ext_vector_type(4))) unsigned int   uvec4;

// ---- d_ws layout (byte offsets; uses ~320 MiB of the 1 GiB ws) ----
#define WS_P0   ((size_t)0)            // bn0 partials: 1024 sets x 16 KB (bf16 sum|sumsq)
#define WS_P1   ((size_t)16 << 20)     // bn1 partials: 1024 sets x 16 KB
#define WS_SC0  ((size_t)48 << 20)     // f32[4096] scale0
#define WS_SH0  (WS_SC0 + 16384)       // f32[4096] shift0
#define WS_SC1  (WS_SC0 + 32768)       // f32[4096] scale1
#define WS_SH1  (WS_SC0 + 49152)       // f32[4096] shift1
#define WS_C1   (WS_SC0 + 65536)       // f32[4096] C1[o][r]
#define WS_C2   (WS_SC0 + 81920)       // f32[4096] C2[o][r]
#define WS_T1   ((size_t)64 << 20)     // t1: 16384 rows x 4 KB fp8 e4m3
#define WS_XB   ((size_t)192 << 20)    // xb: bf16(x), 16384 rows x 8 KB

__device__ __forceinline__ unsigned short f2bf_bits(float f) {
  unsigned u = __builtin_bit_cast(unsigned, f);
  u += 0x7FFFu + ((u >> 16) & 1u);          // round-to-nearest-even
  return (unsigned short)(u >> 16);
}
__device__ __forceinline__ float bf2f(unsigned short b) {
  return __builtin_bit_cast(float, ((unsigned)b) << 16);
}
__device__ __forceinline__ usvec4 pack4(fvec4 a) {
  usvec4 p;
#pragma unroll
  for (int e = 0; e < 4; ++e) p[e] = f2bf_bits(a[e]);
  return p;
}
__device__ __forceinline__ fvec4 unpack4(usvec4 p) {
  return fvec4{bf2f(p[0]), bf2f(p[1]), bf2f(p[2]), bf2f(p[3])};
}
// LDS anti-bank-conflict swizzles (used by BOTH writer and reader).
// swz64: dword-index space with 64-dword rows; XOR bank bits 2..4 with row&7.
__device__ __forceinline__ int swz64(int i) { return i ^ (((i >> 6) & 7) << 2); }
// swz32: 32-dword rows.
__device__ __forceinline__ int swz32(int i) { return i ^ (((i >> 5) & 7) << 2); }

// ---------------- BN0 partial sums + x -> bf16 cast ----------------
__global__ __launch_bounds__(256) void k_bn0part(const float* __restrict__ x,
                                                 unsigned short* __restrict__ p0,
                                                 unsigned short* __restrict__ xb) {
  const int t = threadIdx.x, p = blockIdx.x;          // 1024 blocks, 16 rows each
  fvec4 s[4], sq[4];
#pragma unroll
  for (int q = 0; q < 4; ++q) { s[q] = fvec4{0.f,0.f,0.f,0.f}; sq[q] = s[q]; }
  for (int r = p * 16; r < p * 16 + 16; ++r) {
    const fvec4* row = (const fvec4*)(x + (size_t)r * NFEAT);
    usvec4* xrow = (usvec4*)(xb + (size_t)r * NFEAT);
#pragma unroll
    for (int q = 0; q < 4; ++q) {
      fvec4 v = row[t + 256 * q];
      s[q] += v; sq[q] += v * v;
      xrow[t + 256 * q] = pack4(v);
    }
  }
#pragma unroll
  for (int q = 0; q < 4; ++q) {
    int f0 = (t + 256 * q) * 4;
    *(usvec4*)(p0 + (size_t)p * 8192 + f0)        = pack4(s[q]);
    *(usvec4*)(p0 + (size_t)p * 8192 + 4096 + f0) = pack4(sq[q]);
  }
}

// ---------------- shared reduce body: bf16 partials -> f32 scale|shift ----------------
__device__ __forceinline__ void red_body(fvec4 (*red)[16][2],
                                         const unsigned short* __restrict__ parts,
                                         int nsets,
                                         const float* __restrict__ g,
                                         const float* __restrict__ bta,
                                         float* __restrict__ sc_out,
                                         float* __restrict__ sh_out, int j) {
  const int t = threadIdx.x;
  const int fc = t & 15, c = t >> 4;
  const int v = j * 64 + fc * 4;
  fvec4 s = fvec4{0.f,0.f,0.f,0.f}, q = s;
  for (int i = c; i < nsets; i += 16) {
    s += unpack4(*(const usvec4*)(parts + (size_t)i * 8192 + v));
    q += unpack4(*(const usvec4*)(parts + (size_t)i * 8192 + 4096 + v));
  }
  red[c][fc][0] = s; red[c][fc][1] = q;
  __syncthreads();
  if (c == 0) {
    fvec4 S = red[0][fc][0], Q = red[0][fc][1];
#pragma unroll
    for (int k = 1; k < 16; ++k) { S += red[k][fc][0]; Q += red[k][fc][1]; }
    fvec4 SC, SH;
    const float inv = 1.0f / NROWS;
#pragma unroll
    for (int e = 0; e < 4; ++e) {
      float mean = S[e] * inv;
      float var  = Q[e] * inv - mean * mean;
      float scv  = g[v + e] * rsqrtf(var + 1e-3f);
      SC[e] = scv; SH[e] = bta[v + e] - mean * scv;
    }
    *(fvec4*)(sc_out + v) = SC;
    *(fvec4*)(sh_out + v) = SH;
  }
}

// ---------------- prep0: red0 (blocks 0-63) + C1/C2 (blocks 64-95) ----------------
__global__ __launch_bounds__(256) void k_prep0(const unsigned short* __restrict__ p0,
                                               const float* __restrict__ g0,
                                               const float* __restrict__ b0,
                                               float* __restrict__ sc0,
                                               float* __restrict__ sh0,
                                               const float* __restrict__ lb1,
                                               const float* __restrict__ rw1,
                                               const float* __restrict__ rb1,
                                               const float* __restrict__ lb2,
                                               const float* __restrict__ rw2,
                                               const float* __restrict__ rb2,
                                               float* __restrict__ c1,
                                               float* __restrict__ c2) {
  __shared__ fvec4 red[16][16][2];
  if (blockIdx.x < 64) {
    red_body(red, p0, 1024, g0, b0, sc0, sh0, blockIdx.x);
  } else {
    const int bb   = blockIdx.x - 64;
    const int idx  = (bb & 15) * 256 + threadIdx.x;   // 0..4095
    const int part = bb >> 4;                          // 0 -> C1, 1 -> C2
    const float* lb = part ? lb2 : lb1;
    const float* rw = part ? rw2 : rw1;
    const float* rb = part ? rb2 : rb1;
    int r = idx >> 6, o = idx & 63;
    float acc = rb[o * 64 + r];
    for (int j = 0; j < 64; ++j) acc += lb[o * 64 + j] * rw[j * 64 + r];
    (part ? c2 : c1)[o * 64 + r] = acc;                // C[o][r]
  }
}

// ---------------- bn1stat: t1(fp8) -> bf16 partial sums ----------------
__global__ __launch_bounds__(256) void k_bn1stat(const unsigned char* __restrict__ t1q,
                                                 unsigned short* __restrict__ p1) {
  const int t = threadIdx.x, p = blockIdx.x;          // 1024 blocks, 16 rows each
  float s[16], q[16];
#pragma unroll
  for (int i = 0; i < 16; ++i) { s[i] = 0.f; q[i] = 0.f; }
  for (int r = p * 16; r < p * 16 + 16; ++r) {
    uvec4 v = *(const uvec4*)(t1q + (size_t)r * NFEAT + t * 16);
#pragma unroll
    for (int d = 0; d < 4; ++d) {
      fvec2 lo = __builtin_amdgcn_cvt_pk_f32_fp8((int)v[d], false);
      fvec2 hi = __builtin_amdgcn_cvt_pk_f32_fp8((int)v[d], true);
      float e0 = lo[0], e1 = lo[1], e2 = hi[0], e3 = hi[1];
      s[d*4+0] += e0; q[d*4+0] += e0*e0;
      s[d*4+1] += e1; q[d*4+1] += e1*e1;
      s[d*4+2] += e2; q[d*4+2] += e2*e2;
      s[d*4+3] += e3; q[d*4+3] += e3*e3;
    }
  }
#pragma unroll
  for (int b4 = 0; b4 < 4; ++b4) {
    fvec4 sv{s[b4*4], s[b4*4+1], s[b4*4+2], s[b4*4+3]};
    fvec4 qv{q[b4*4], q[b4*4+1], q[b4*4+2], q[b4*4+3]};
    *(usvec4*)(p1 + (size_t)p * 8192 + t * 16 + b4 * 4)        = pack4(sv);
    *(usvec4*)(p1 + (size_t)p * 8192 + 4096 + t * 16 + b4 * 4) = pack4(qv);
  }
}

// ---------------- red1: bn1 partials -> scale1|shift1 ----------------
__global__ __launch_bounds__(256) void k_red1(const unsigned short* __restrict__ p1,
                                              const float* __restrict__ g1,
                                              const float* __restrict__ b1,
                                              float* __restrict__ sc1,
                                              float* __restrict__ sh1) {
  __shared__ fvec4 red[16][16][2];
  red_body(red, p1, 1024, g1, b1, sc1, sh1, blockIdx.x);
}

// ---------------- kron: ONE WAVE PER ROW, wave-local fences only ----------------
// Per row b: X[k][j] (64x64, post BN+relu bf16).  mm1: V = X*RW (4 kt x 4 rt tiles).
// V^T staged in this wave's PRIVATE 8KB LDS region; a wave-local
// {sched_barrier; s_waitcnt lgkmcnt(0); sched_barrier} fence orders mm1 ds_writes
// before mm2 ds_reads (no cross-wave s_barrier anywhere in the loop).
// LAYER==1: A-src xb(bf16)+BN0 -> t1 fp8.  LAYER==2: A-src t1(fp8)+BN1 -> x+Z+C2.
template <int LAYER>
__global__ __launch_bounds__(256, 2) void k_kron(const unsigned short* __restrict__ xb,
                                                 const unsigned char* __restrict__ t1r,
                                                 const float* __restrict__ lw,
                                                 const float* __restrict__ rw,
                                                 const float* __restrict__ scv,
                                                 const float* __restrict__ shv,
                                                 const float* __restrict__ cn,
                                                 unsigned char* __restrict__ t1w,
                                                 float* __restrict__ outf) {
  __shared__ __align__(16) unsigned short vt[4][4096];  // per-wave private V^T (8 KB each)
  __shared__ __align__(16) unsigned scsh[4096];  // dword f: {lo: bf16 sc[f], hi: bf16 sh[f]}, swz64
  __shared__ __align__(16) unsigned cbl[2048];   // dword d: bf16 pair {C[o][2r'],C[o][2r'+1]}, swz32
  const int tid = threadIdx.x, bid = blockIdx.x;
  const int w = tid >> 6, l = tid & 63, m = l & 15, g = l >> 4;
  unsigned short* vtw = &vt[w][0];

  // ---- prologue staging (one __syncthreads, the only cross-wave barrier) ----
#pragma unroll
  for (int c = 0; c < 16; ++c) {
    int f = tid * 16 + c;                                // 0..4095
    scsh[swz64(f)] = (unsigned)f2bf_bits(scv[f]) | ((unsigned)f2bf_bits(shv[f]) << 16);
  }
#pragma unroll
  for (int c = 0; c < 8; ++c) {
    int d = tid * 8 + c;                                 // 0..2047
    int o = d >> 5, pr = (d & 31) * 2;
    cbl[swz32(d)] = (unsigned)f2bf_bits(cn[o * 64 + pr]) |
                    ((unsigned)f2bf_bits(cn[o * 64 + pr + 1]) << 16);
  }
  // zero this wave's vt region: any residual coverage bug reads 0.0, not NaN garbage
#pragma unroll
  for (int c = 0; c < 8; ++c)
    *(uvec4*)((char*)vtw + l * 128 + c * 16) = uvec4{0u, 0u, 0u, 0u};

  // RW B-frags: frw[rt][ks][i] = RW[ks*32+g*8+i][rt*16+m]
  bfrag8 frw[4][2];
#pragma unroll
  for (int rt = 0; rt < 4; ++rt)
#pragma unroll
    for (int ks = 0; ks < 2; ++ks)
#pragma unroll
      for (int i = 0; i < 8; ++i)
        frw[rt][ks][i] = (short)f2bf_bits(rw[(ks * 32 + g * 8 + i) * 64 + rt * 16 + m]);

  // LW B-frags: flw[ot][ks][i] = LW[ks*32+g*8+i][ot*16+m]
  bfrag8 flw[4][2];
#pragma unroll
  for (int ot = 0; ot < 4; ++ot)
#pragma unroll
    for (int ks = 0; ks < 2; ++ks)
#pragma unroll
      for (int i = 0; i < 8; ++i)
        flw[ot][ks][i] = (short)f2bf_bits(lw[(ks * 32 + g * 8 + i) * 64 + ot * 16 + m]);

  __syncthreads();

  const int r0w = bid * 32 + w * 8;        // this wave's 8 contiguous rows

  usvec8 sA0[8], sA1[8];                   // LAYER1 staging (cur/next row)
  uvec2  sQ0[8], sQ1[8];                   // LAYER2 staging

  if constexpr (LAYER == 1) {
    const usvec8* p = (const usvec8*)(xb + (size_t)r0w * NFEAT);
#pragma unroll
    for (int kt = 0; kt < 4; ++kt)
#pragma unroll
      for (int ks = 0; ks < 2; ++ks)
        sA0[kt * 2 + ks] = p[(kt * 16 + m) * 8 + ks * 4 + g];
  } else {
    const uvec2* p = (const uvec2*)(t1r + (size_t)r0w * NFEAT);
#pragma unroll
    for (int kt = 0; kt < 4; ++kt)
#pragma unroll
      for (int ks = 0; ks < 2; ++ks)
        sQ0[kt * 2 + ks] = p[(kt * 16 + m) * 8 + ks * 4 + g];
  }

  auto row_body = [&](int rrow, usvec8 (&curA)[8], usvec8 (&nxtA)[8],
                      uvec2 (&curQ)[8], uvec2 (&nxtQ)[8], bool pf) {
    // ---- issue next-row loads (hidden under this row's compute) ----
    if (pf) {
      if constexpr (LAYER == 1) {
        const usvec8* p = (const usvec8*)(xb + (size_t)(rrow + 1) * NFEAT);
#pragma unroll
        for (int kt = 0; kt < 4; ++kt)
#pragma unroll
          for (int ks = 0; ks < 2; ++ks)
            nxtA[kt * 2 + ks] = p[(kt * 16 + m) * 8 + ks * 4 + g];
      } else {
        const uvec2* p = (const uvec2*)(t1r + (size_t)(rrow + 1) * NFEAT);
#pragma unroll
        for (int kt = 0; kt < 4; ++kt)
#pragma unroll
          for (int ks = 0; ks < 2; ++ks)
            nxtQ[kt * 2 + ks] = p[(kt * 16 + m) * 8 + ks * 4 + g];
      }
    }
    // LAYER2: issue residual loads for current row (consumed in epilogue)
    usvec4 res[16];
    if constexpr (LAYER == 2) {
#pragma unroll
      for (int ot = 0; ot < 4; ++ot)
#pragma unroll
        for (int rt2 = 0; rt2 < 4; ++rt2)
          res[ot * 4 + rt2] = *(const usvec4*)(xb + (size_t)rrow * NFEAT +
                                               (ot * 16 + m) * 64 + rt2 * 16 + g * 4);
    }

    // ---- mm1: V = X*RW, write V^T into private LDS ----
#pragma unroll
    for (int kt = 0; kt < 4; ++kt) {
      bfrag8 fa[2];
#pragma unroll
      for (int ks = 0; ks < 2; ++ks) {
        int f0 = (kt * 16 + m) * 64 + ks * 32 + g * 8;
        uvec4 c0  = *(const uvec4*)&scsh[swz64(f0)];
        uvec4 c1v = *(const uvec4*)&scsh[swz64(f0 + 4)];
        float xs[8];
        if constexpr (LAYER == 1) {
          usvec8 tv = curA[kt * 2 + ks];
#pragma unroll
          for (int i = 0; i < 8; ++i) xs[i] = bf2f(tv[i]);
        } else {
          uvec2 tv = curQ[kt * 2 + ks];
          fvec2 d0 = __builtin_amdgcn_cvt_pk_f32_fp8((int)tv[0], false);
          fvec2 d1 = __builtin_amdgcn_cvt_pk_f32_fp8((int)tv[0], true);
          fvec2 d2 = __builtin_amdgcn_cvt_pk_f32_fp8((int)tv[1], false);
          fvec2 d3 = __builtin_amdgcn_cvt_pk_f32_fp8((int)tv[1], true);
          xs[0]=d0[0]; xs[1]=d0[1]; xs[2]=d1[0]; xs[3]=d1[1];
          xs[4]=d2[0]; xs[5]=d2[1]; xs[6]=d3[0]; xs[7]=d3[1];
        }
        usvec8 u;
#pragma unroll
        for (int i = 0; i < 8; ++i) {
          unsigned dw = (i < 4) ? c0[i] : c1v[i - 4];
          float scf = __builtin_bit_cast(float, dw << 16);
          float shf = __builtin_bit_cast(float, dw & 0xffff0000u);
          u[i] = f2bf_bits(fmaxf(fmaf(xs[i], scf, shf), 0.f));
        }
        fa[ks] = __builtin_bit_cast(bfrag8, u);
      }
#pragma unroll
      for (int rt = 0; rt < 4; ++rt) {
        fvec4 va = fvec4{0.f, 0.f, 0.f, 0.f};
        va = __builtin_amdgcn_mfma_f32_16x16x32_bf16(fa[0], frw[rt][0], va, 0, 0, 0);
        va = __builtin_amdgcn_mfma_f32_16x16x32_bf16(fa[1], frw[rt][1], va, 0, 0, 0);
        int ridx = rt * 16 + m;
        int chunk = 2 * kt + (g >> 1);
        int byte = ridx * 128 + ((chunk ^ (ridx & 7)) << 4) + (g & 1) * 8;
        *(usvec4*)((char*)vtw + byte) = pack4(va);
      }
    }

    // ---- wave-local fence: mm1 ds_writes complete before mm2 ds_reads issue;
    //      vmcnt untouched so global prefetch/stores stay in flight ----
    __builtin_amdgcn_sched_barrier(0);
    asm volatile("s_waitcnt lgkmcnt(0)");
    __builtin_amdgcn_sched_barrier(0);

    // ---- mm2: Z^T = V^T * LW ----
#pragma unroll
    for (int rt2 = 0; rt2 < 4; ++rt2) {
      int ridx = rt2 * 16 + m;
      bfrag8 a0 = *(const bfrag8*)((const char*)vtw +
                    ridx * 128 + (((0 + g) ^ (ridx & 7)) << 4));
      bfrag8 a1 = *(const bfrag8*)((const char*)vtw +
                    ridx * 128 + (((4 + g) ^ (ridx & 7)) << 4));
      fvec4 acc[4];
#pragma unroll
      for (int ot = 0; ot < 4; ++ot) {
        acc[ot] = fvec4{0.f, 0.f, 0.f, 0.f};
        acc[ot] = __builtin_amdgcn_mfma_f32_16x16x32_bf16(a0, flw[ot][0], acc[ot], 0, 0, 0);
        acc[ot] = __builtin_amdgcn_mfma_f32_16x16x32_bf16(a1, flw[ot][1], acc[ot], 0, 0, 0);
      }
#pragma unroll
      for (int ot = 0; ot < 4; ++ot) {
        int dcb = (ot * 16 + m) * 32 + rt2 * 8 + 2 * g;
        uvec2 cv = *(const uvec2*)&cbl[swz32(dcb)];
        fvec4 cb4{__builtin_bit_cast(float, cv[0] << 16),
                  __builtin_bit_cast(float, cv[0] & 0xffff0000u),
                  __builtin_bit_cast(float, cv[1] << 16),
                  __builtin_bit_cast(float, cv[1] & 0xffff0000u)};
        fvec4 z = acc[ot] + cb4;
        int foff = (ot * 16 + m) * 64 + rt2 * 16 + g * 4;
        if constexpr (LAYER == 1) {
          int pq = __builtin_amdgcn_cvt_pk_fp8_f32(z[0], z[1], 0, false);
          pq     = __builtin_amdgcn_cvt_pk_fp8_f32(z[2], z[3], pq, true);
          *(unsigned*)(t1w + (size_t)rrow * NFEAT + foff) = (unsigned)pq;
        } else {
          *(fvec4*)(outf + (size_t)rrow * NFEAT + foff) =
              unpack4(res[ot * 4 + rt2]) + z;
        }
      }
    }
  };

  for (int rp = 0; rp < 4; ++rp) {
    row_body(r0w + 2 * rp,     sA0, sA1, sQ0, sQ1, true);
    row_body(r0w + 2 * rp + 1, sA1, sA0, sQ1, sQ0, rp < 3);
  }
}

extern "C" void kernel_launch(void* const* d_in, const int* in_sizes, int n_in,
                              void* d_out, int out_size, void* d_ws, size_t ws_size,
                              hipStream_t stream) {
  (void)in_sizes; (void)n_in; (void)out_size; (void)ws_size;
  const float* x    = (const float*)d_in[0];
  const float* g0   = (const float*)d_in[1];
  const float* b0   = (const float*)d_in[2];
  const float* g1   = (const float*)d_in[3];
  const float* b1   = (const float*)d_in[4];
  const float* k1lw = (const float*)d_in[5];
  const float* k1lb = (const float*)d_in[6];
  const float* k1rw = (const float*)d_in[7];
  const float* k1rb = (const float*)d_in[8];
  const float* k2lw = (const float*)d_in[9];
  const float* k2lb = (const float*)d_in[10];
  const float* k2rw = (const float*)d_in[11];
  const float* k2rb = (const float*)d_in[12];
  char* ws = (char*)d_ws;

  unsigned short* p0  = (unsigned short*)(ws + WS_P0);
  unsigned short* p1  = (unsigned short*)(ws + WS_P1);
  unsigned char*  t1q = (unsigned char*)(ws + WS_T1);
  unsigned short* xb  = (unsigned short*)(ws + WS_XB);
  float* sc0 = (float*)(ws + WS_SC0);
  float* sh0 = (float*)(ws + WS_SH0);
  float* sc1 = (float*)(ws + WS_SC1);
  float* sh1 = (float*)(ws + WS_SH1);
  float* c1  = (float*)(ws + WS_C1);
  float* c2  = (float*)(ws + WS_C2);

  k_bn0part<<<1024, 256, 0, stream>>>(x, p0, xb);
  k_prep0<<<96, 256, 0, stream>>>(p0, g0, b0, sc0, sh0,
                                  k1lb, k1rw, k1rb, k2lb, k2rw, k2rb, c1, c2);
  k_kron<1><<<512, 256, 0, stream>>>(xb, nullptr, k1lw, k1rw, sc0, sh0, c1,
                                     t1q, nullptr);
  k_bn1stat<<<1024, 256, 0, stream>>>(t1q, p1);
  k_red1<<<64, 256, 0, stream>>>(p1, g1, b1, sc1, sh1);
  k_kron<2><<<512, 256, 0, stream>>>(xb, t1q, k2lw, k2rw, sc1, sh1, c2,
                                     t1q, (float*)d_out);
}